// Round 1
// baseline (1103.166 us; speedup 1.0000x reference)
//
#include <hip/hip_runtime.h>
#include <hip/hip_bf16.h>
#include <math.h>

#define N_NODES 100000
#define N_EDGES 1600000
#define E_TOT   1700000   // edges + self loops
#define NEG_SLOPE 0.2f
#define SCAN_NB 98        // ceil(100000/1024)

__device__ __forceinline__ float lrelu(float v) { return v > 0.f ? v : NEG_SLOPE * v; }

// ---------------- GEMM1: h1[N,128] = x[N,128] @ W1[128,128] ----------------
// wave owns 8 rows (uniform loads), lane owns 2 cols. 3125 blocks x 256.
__global__ __launch_bounds__(256) void k_gemm1(const float* __restrict__ x,
                                               const float* __restrict__ W,
                                               float* __restrict__ h)
{
    const int t = threadIdx.x;
    const int lane = t & 63;
    const int wv = t >> 6;
    const long row0 = (long)blockIdx.x * 32 + wv * 8;
    const int c0 = lane * 2;

    float2 acc[8];
#pragma unroll
    for (int i = 0; i < 8; ++i) acc[i] = make_float2(0.f, 0.f);

    const float* xrow = x + row0 * 128;
    for (int k = 0; k < 128; k += 4) {
        float4 xv[8];
#pragma unroll
        for (int i = 0; i < 8; ++i) xv[i] = *(const float4*)(xrow + i * 128 + k);
#pragma unroll
        for (int kk = 0; kk < 4; ++kk) {
            const float2 w2 = *(const float2*)(W + (k + kk) * 128 + c0);
#pragma unroll
            for (int i = 0; i < 8; ++i) {
                const float xs = kk == 0 ? xv[i].x : kk == 1 ? xv[i].y : kk == 2 ? xv[i].z : xv[i].w;
                acc[i].x = fmaf(xs, w2.x, acc[i].x);
                acc[i].y = fmaf(xs, w2.y, acc[i].y);
            }
        }
    }
#pragma unroll
    for (int i = 0; i < 8; ++i)
        *(float2*)(h + (row0 + i) * 128 + c0) = acc[i];
}

// ---------------- alpha1: as1/ad1 [N,4] ----------------
__global__ __launch_bounds__(256) void k_alpha1(const float* __restrict__ h,
                                                const float* __restrict__ a_src,
                                                const float* __restrict__ a_dst,
                                                float* __restrict__ as_,
                                                float* __restrict__ ad_)
{
    const int tid = blockIdx.x * 256 + threadIdx.x;
    if (tid >= N_NODES * 4) return;
    const int hh = tid & 3;
    const float4* hv = (const float4*)(h + (size_t)(tid >> 2) * 128 + hh * 32);
    const float4* av = (const float4*)(a_src + hh * 32);
    const float4* bv = (const float4*)(a_dst + hh * 32);
    float s = 0.f, d = 0.f;
#pragma unroll
    for (int i = 0; i < 8; ++i) {
        const float4 v = hv[i], a = av[i], b = bv[i];
        s += v.x * a.x + v.y * a.y + v.z * a.z + v.w * a.w;
        d += v.x * b.x + v.y * b.y + v.z * b.z + v.w * b.w;
    }
    as_[tid] = s; ad_[tid] = d;
}

// ---------------- CSR build ----------------
__global__ __launch_bounds__(256) void k_hist(const int* __restrict__ ei, int* __restrict__ deg)
{
    const int e = blockIdx.x * 256 + threadIdx.x;
    if (e >= E_TOT) return;
    const int d = (e < N_EDGES) ? ei[N_EDGES + e] : (e - N_EDGES);
    atomicAdd(&deg[d], 1);
}

__global__ __launch_bounds__(256) void k_scan_a(const int* __restrict__ deg, int* __restrict__ bsum)
{
    __shared__ int sd[256];
    const int b = blockIdx.x, t = threadIdx.x;
    const int base = b * 1024 + t * 4;
    int s = 0;
#pragma unroll
    for (int i = 0; i < 4; ++i) { const int idx = base + i; if (idx < N_NODES) s += deg[idx]; }
    sd[t] = s; __syncthreads();
    for (int off = 128; off > 0; off >>= 1) {
        if (t < off) sd[t] += sd[t + off];
        __syncthreads();
    }
    if (t == 0) bsum[b] = sd[0];
}

__global__ void k_scan_b(const int* __restrict__ bsum, int* __restrict__ bscan)
{
    if (threadIdx.x == 0) {
        int run = 0;
        for (int i = 0; i < SCAN_NB; ++i) { bscan[i] = run; run += bsum[i]; }
    }
}

__global__ __launch_bounds__(256) void k_scan_c(const int* __restrict__ deg,
                                                const int* __restrict__ bscan,
                                                int* __restrict__ row_ptr,
                                                int* __restrict__ cursor)
{
    __shared__ int sd[256];
    const int b = blockIdx.x, t = threadIdx.x;
    const int base = b * 1024 + t * 4;
    int v0 = 0, v1 = 0, v2 = 0, v3 = 0;
    if (base + 0 < N_NODES) v0 = deg[base + 0];
    if (base + 1 < N_NODES) v1 = deg[base + 1];
    if (base + 2 < N_NODES) v2 = deg[base + 2];
    if (base + 3 < N_NODES) v3 = deg[base + 3];
    const int tot = v0 + v1 + v2 + v3;
    sd[t] = tot; __syncthreads();
    for (int off = 1; off < 256; off <<= 1) {
        int xv = 0;
        if (t >= off) xv = sd[t - off];
        __syncthreads();
        if (t >= off) sd[t] += xv;
        __syncthreads();
    }
    int run = bscan[b] + sd[t] - tot;   // exclusive prefix for this thread
    if (base + 0 < N_NODES) { row_ptr[base + 0] = run; cursor[base + 0] = run; run += v0; }
    if (base + 1 < N_NODES) { row_ptr[base + 1] = run; cursor[base + 1] = run; run += v1; }
    if (base + 2 < N_NODES) { row_ptr[base + 2] = run; cursor[base + 2] = run; run += v2; }
    if (base + 3 < N_NODES) { row_ptr[base + 3] = run; cursor[base + 3] = run; run += v3; }
    if (b == 0 && t == 0) row_ptr[N_NODES] = E_TOT;
}

__global__ __launch_bounds__(256) void k_fill(const int* __restrict__ ei,
                                              int* __restrict__ cursor,
                                              int* __restrict__ col_src)
{
    const int e = blockIdx.x * 256 + threadIdx.x;
    if (e >= E_TOT) return;
    int s, d;
    if (e < N_EDGES) { s = ei[e]; d = ei[N_EDGES + e]; }
    else { s = d = e - N_EDGES; }
    const int pos = atomicAdd(&cursor[d], 1);
    col_src[pos] = s;
}

// ---------------- agg1: GAT layer-1 aggregation + bias + ELU -> x2[N,128] ----------------
__global__ __launch_bounds__(64) void k_agg1(const float* __restrict__ h,
                                             const float* __restrict__ as_,
                                             const float* __restrict__ ad_,
                                             const int* __restrict__ row_ptr,
                                             const int* __restrict__ col_src,
                                             const float* __restrict__ bias,
                                             float* __restrict__ x2)
{
    __shared__ float sEx[256];
    __shared__ int sSrc[64];
    const int n = blockIdx.x;
    const int lane = threadIdx.x;
    const int start = row_ptr[n], end = row_ptr[n + 1];
    const float4 adv = *(const float4*)(ad_ + (size_t)n * 4);

    // pass A: per-head max over incoming edges
    float4 mx = make_float4(-1e30f, -1e30f, -1e30f, -1e30f);
    for (int base = start; base < end; base += 64) {
        const int e = base + lane;
        if (e < end) {
            const float4 av = *(const float4*)(as_ + (size_t)col_src[e] * 4);
            mx.x = fmaxf(mx.x, lrelu(av.x + adv.x));
            mx.y = fmaxf(mx.y, lrelu(av.y + adv.y));
            mx.z = fmaxf(mx.z, lrelu(av.z + adv.z));
            mx.w = fmaxf(mx.w, lrelu(av.w + adv.w));
        }
    }
#pragma unroll
    for (int off = 32; off > 0; off >>= 1) {
        mx.x = fmaxf(mx.x, __shfl_xor(mx.x, off));
        mx.y = fmaxf(mx.y, __shfl_xor(mx.y, off));
        mx.z = fmaxf(mx.z, __shfl_xor(mx.z, off));
        mx.w = fmaxf(mx.w, __shfl_xor(mx.w, off));
    }

    // pass B: weighted gather-accumulate (unnormalized) + denom
    const int hsel = lane >> 4;       // head of this lane's 2 channels
    const int c0 = lane * 2;
    float2 acc = make_float2(0.f, 0.f);
    float4 ds = make_float4(0.f, 0.f, 0.f, 0.f);
    for (int base = start; base < end; base += 64) {
        const int e = base + lane;
        const int cnt = min(64, end - base);
        float4 ex = make_float4(0.f, 0.f, 0.f, 0.f);
        int s = 0;
        if (e < end) {
            s = col_src[e];
            const float4 av = *(const float4*)(as_ + (size_t)s * 4);
            ex.x = __expf(lrelu(av.x + adv.x) - mx.x);
            ex.y = __expf(lrelu(av.y + adv.y) - mx.y);
            ex.z = __expf(lrelu(av.z + adv.z) - mx.z);
            ex.w = __expf(lrelu(av.w + adv.w) - mx.w);
            ds.x += ex.x; ds.y += ex.y; ds.z += ex.z; ds.w += ex.w;
        }
        __syncthreads();
        *(float4*)(sEx + lane * 4) = ex;
        sSrc[lane] = s;
        __syncthreads();
        for (int i = 0; i < cnt; ++i) {
            const float w = sEx[i * 4 + hsel];
            const float2 hv = *(const float2*)(h + (size_t)sSrc[i] * 128 + c0);
            acc.x = fmaf(w, hv.x, acc.x);
            acc.y = fmaf(w, hv.y, acc.y);
        }
    }
#pragma unroll
    for (int off = 32; off > 0; off >>= 1) {
        ds.x += __shfl_xor(ds.x, off);
        ds.y += __shfl_xor(ds.y, off);
        ds.z += __shfl_xor(ds.z, off);
        ds.w += __shfl_xor(ds.w, off);
    }
    const float denom = hsel == 0 ? ds.x : hsel == 1 ? ds.y : hsel == 2 ? ds.z : ds.w;
    float o0 = acc.x / denom + bias[c0];
    float o1 = acc.y / denom + bias[c0 + 1];
    o0 = o0 > 0.f ? o0 : __expf(o0) - 1.f;   // ELU
    o1 = o1 > 0.f ? o1 : __expf(o1) - 1.f;
    *(float2*)(x2 + (size_t)n * 128 + c0) = make_float2(o0, o1);
}

// ---------------- GEMM2: h2[N,32] = x2[N,128] @ W2[128,32], fused alpha2 ----------------
// 64 rows/block: wave = 16 rows (2 half-waves x 8 rows), lane&31 = col.
__global__ __launch_bounds__(256) void k_gemm2(const float* __restrict__ x2,
                                               const float* __restrict__ W,
                                               const float* __restrict__ a_src,
                                               const float* __restrict__ a_dst,
                                               float* __restrict__ h2,
                                               float* __restrict__ as_,
                                               float* __restrict__ ad_)
{
    __shared__ float sW[128 * 32];
    const int t = threadIdx.x;
    {
        const float4* W4 = (const float4*)W;
        float4* sW4 = (float4*)sW;
#pragma unroll
        for (int i = 0; i < 4; ++i) sW4[t + 256 * i] = W4[t + 256 * i];
    }
    __syncthreads();

    const int lane = t & 63, wv = t >> 6;
    const int c = lane & 31, rh = lane >> 5;
    const long rowbase = (long)blockIdx.x * 64 + wv * 16 + rh * 8;
    const long rload = rowbase > (long)(N_NODES - 8) ? (long)(N_NODES - 8) : rowbase;
    const float* xp = x2 + rload * 128;

    float acc[8];
#pragma unroll
    for (int i = 0; i < 8; ++i) acc[i] = 0.f;

    for (int k = 0; k < 128; k += 4) {
        float4 xv[8];
#pragma unroll
        for (int i = 0; i < 8; ++i) xv[i] = *(const float4*)(xp + i * 128 + k);
#pragma unroll
        for (int kk = 0; kk < 4; ++kk) {
            const float w = sW[(k + kk) * 32 + c];
#pragma unroll
            for (int i = 0; i < 8; ++i) {
                const float xs = kk == 0 ? xv[i].x : kk == 1 ? xv[i].y : kk == 2 ? xv[i].z : xv[i].w;
                acc[i] = fmaf(xs, w, acc[i]);
            }
        }
    }

    const float a_s = a_src[c], a_d = a_dst[c];
#pragma unroll
    for (int i = 0; i < 8; ++i) {
        const long r = rowbase + i;
        float ps = acc[i] * a_s, pd = acc[i] * a_d;
#pragma unroll
        for (int off = 16; off > 0; off >>= 1) {
            ps += __shfl_xor(ps, off);
            pd += __shfl_xor(pd, off);
        }
        if (r < N_NODES) {
            h2[r * 32 + c] = acc[i];
            if (c == 0) { as_[r] = ps; ad_[r] = pd; }
        }
    }
}

// ---------------- agg2: GAT layer-2 aggregation + bias -> out[N,32] ----------------
__global__ __launch_bounds__(64) void k_agg2(const float* __restrict__ h,
                                             const float* __restrict__ as_,
                                             const float* __restrict__ ad_,
                                             const int* __restrict__ row_ptr,
                                             const int* __restrict__ col_src,
                                             const float* __restrict__ bias,
                                             float* __restrict__ out)
{
    __shared__ float sEx[64];
    __shared__ int sSrc[64];
    const int n = blockIdx.x;
    const int lane = threadIdx.x;
    const int start = row_ptr[n], end = row_ptr[n + 1];
    const float adn = ad_[n];

    float mx = -1e30f;
    for (int base = start; base < end; base += 64) {
        const int e = base + lane;
        if (e < end) mx = fmaxf(mx, lrelu(as_[col_src[e]] + adn));
    }
#pragma unroll
    for (int off = 32; off > 0; off >>= 1) mx = fmaxf(mx, __shfl_xor(mx, off));

    const int c = lane & 31, half = lane >> 5;
    float acc = 0.f, dsum = 0.f;
    for (int base = start; base < end; base += 64) {
        const int e = base + lane;
        const int cnt = min(64, end - base);
        float ex = 0.f; int s = 0;
        if (e < end) {
            s = col_src[e];
            ex = __expf(lrelu(as_[s] + adn) - mx);
            dsum += ex;
        }
        __syncthreads();
        sEx[lane] = ex;
        sSrc[lane] = s;
        __syncthreads();
        for (int i = half; i < cnt; i += 2)
            acc = fmaf(sEx[i], h[(size_t)sSrc[i] * 32 + c], acc);
    }
#pragma unroll
    for (int off = 32; off > 0; off >>= 1) dsum += __shfl_xor(dsum, off);
    acc += __shfl_xor(acc, 32);
    if (half == 0) out[(size_t)n * 32 + c] = acc / dsum + bias[c];
}

extern "C" void kernel_launch(void* const* d_in, const int* in_sizes, int n_in,
                              void* d_out, int out_size, void* d_ws, size_t ws_size,
                              hipStream_t stream)
{
    const float* x      = (const float*)d_in[0];
    const int*   ei     = (const int*)d_in[1];
    const float* W1     = (const float*)d_in[2];
    const float* a_src1 = (const float*)d_in[3];
    const float* a_dst1 = (const float*)d_in[4];
    const float* b1     = (const float*)d_in[5];
    const float* W2     = (const float*)d_in[6];
    const float* a_src2 = (const float*)d_in[7];
    const float* a_dst2 = (const float*)d_in[8];
    const float* b2     = (const float*)d_in[9];
    float* out = (float*)d_out;

    char* p = (char*)d_ws;
    auto alloc = [&](size_t bytes) { char* q = p; p += (bytes + 255) & ~(size_t)255; return q; };
    float* h1    = (float*)alloc((size_t)N_NODES * 128 * 4);
    float* x2    = (float*)alloc((size_t)N_NODES * 128 * 4);
    float* h2    = (float*)alloc((size_t)N_NODES * 32 * 4);
    float* as1   = (float*)alloc((size_t)N_NODES * 4 * 4);
    float* ad1   = (float*)alloc((size_t)N_NODES * 4 * 4);
    float* as2   = (float*)alloc((size_t)N_NODES * 4);
    float* ad2   = (float*)alloc((size_t)N_NODES * 4);
    int* deg     = (int*)alloc((size_t)N_NODES * 4);
    int* row_ptr = (int*)alloc((size_t)(N_NODES + 1) * 4);
    int* cursor  = (int*)alloc((size_t)N_NODES * 4);
    int* bsum    = (int*)alloc(SCAN_NB * 4);
    int* bscan   = (int*)alloc(SCAN_NB * 4);
    int* col_src = (int*)alloc((size_t)E_TOT * 4);

    hipMemsetAsync(deg, 0, (size_t)N_NODES * 4, stream);

    k_gemm1<<<N_NODES / 32, 256, 0, stream>>>(x, W1, h1);
    k_alpha1<<<(N_NODES * 4 + 255) / 256, 256, 0, stream>>>(h1, a_src1, a_dst1, as1, ad1);
    k_hist<<<(E_TOT + 255) / 256, 256, 0, stream>>>(ei, deg);
    k_scan_a<<<SCAN_NB, 256, 0, stream>>>(deg, bsum);
    k_scan_b<<<1, 64, 0, stream>>>(bsum, bscan);
    k_scan_c<<<SCAN_NB, 256, 0, stream>>>(deg, bscan, row_ptr, cursor);
    k_fill<<<(E_TOT + 255) / 256, 256, 0, stream>>>(ei, cursor, col_src);
    k_agg1<<<N_NODES, 64, 0, stream>>>(h1, as1, ad1, row_ptr, col_src, b1, x2);
    k_gemm2<<<(N_NODES + 63) / 64, 256, 0, stream>>>(x2, W2, a_src2, a_dst2, h2, as2, ad2);
    k_agg2<<<N_NODES, 64, 0, stream>>>(h2, as2, ad2, row_ptr, col_src, b2, out);
}

// Round 2
// 594.393 us; speedup vs baseline: 1.8560x; 1.8560x over previous
//
#include <hip/hip_runtime.h>
#include <hip/hip_bf16.h>
#include <math.h>

#define N_NODES 100000
#define N_EDGES 1600000
#define E_TOT   1700000   // edges + self loops
#define NEG_SLOPE 0.2f
#define SCAN_NB 98        // ceil(100000/1024)

__device__ __forceinline__ float lrelu(float v) { return v > 0.f ? v : NEG_SLOPE * v; }

// ---------------- GEMM1: h1[N,128] = x[N,128] @ W1[128,128], fused alpha1 ----------------
// block = 256 threads = 4 groups x 64 lanes; group owns 4 rows; lane owns 2 cols.
// W1 staged in 16KB LDS chunks (k-chunks of 32). Register arrays kept small to avoid spill.
__global__ __launch_bounds__(256) void k_gemm1(const float* __restrict__ x,
                                               const float* __restrict__ W,
                                               const float* __restrict__ a_src,
                                               const float* __restrict__ a_dst,
                                               float* __restrict__ h,
                                               float* __restrict__ as_,
                                               float* __restrict__ ad_)
{
    __shared__ float sW[32 * 128];   // one 32-row k-chunk of W1 (16 KB)
    const int t = threadIdx.x;
    const int lane = t & 63, grp = t >> 6;
    const int row0 = blockIdx.x * 16 + grp * 4;   // 6250 blocks * 16 = 100000 exact
    const int c0 = lane * 2;

    float2 acc[4];
#pragma unroll
    for (int i = 0; i < 4; ++i) acc[i] = make_float2(0.f, 0.f);

    for (int kc = 0; kc < 128; kc += 32) {
        __syncthreads();   // protect previous chunk's readers
        {
            const float4* Wsrc = (const float4*)(W + kc * 128);
            float4* sW4 = (float4*)sW;
#pragma unroll
            for (int i = 0; i < 4; ++i) sW4[t + 256 * i] = Wsrc[t + 256 * i];
        }
        __syncthreads();
        const float* xrow = x + (size_t)row0 * 128 + kc;
        for (int k = 0; k < 32; k += 4) {
            float4 xv[4];
#pragma unroll
            for (int i = 0; i < 4; ++i) xv[i] = *(const float4*)(xrow + i * 128 + k);
#pragma unroll
            for (int kk = 0; kk < 4; ++kk) {
                const float2 w2 = *(const float2*)(sW + (k + kk) * 128 + c0);
#pragma unroll
                for (int i = 0; i < 4; ++i) {
                    const float xs = kk == 0 ? xv[i].x : kk == 1 ? xv[i].y : kk == 2 ? xv[i].z : xv[i].w;
                    acc[i].x = fmaf(xs, w2.x, acc[i].x);
                    acc[i].y = fmaf(xs, w2.y, acc[i].y);
                }
            }
        }
    }

    // epilogue: write h1, fused alpha dot-products (16-lane group = one head)
    const float2 asv = *(const float2*)(a_src + c0);
    const float2 adv = *(const float2*)(a_dst + c0);
    const int head = lane >> 4;
#pragma unroll
    for (int i = 0; i < 4; ++i) {
        const int r = row0 + i;
        *(float2*)(h + (size_t)r * 128 + c0) = acc[i];
        float ps = acc[i].x * asv.x + acc[i].y * asv.y;
        float pd = acc[i].x * adv.x + acc[i].y * adv.y;
#pragma unroll
        for (int off = 8; off > 0; off >>= 1) {
            ps += __shfl_xor(ps, off);
            pd += __shfl_xor(pd, off);
        }
        if ((lane & 15) == 0) { as_[r * 4 + head] = ps; ad_[r * 4 + head] = pd; }
    }
}

// ---------------- CSR build ----------------
__global__ __launch_bounds__(256) void k_hist(const int* __restrict__ ei, int* __restrict__ deg)
{
    const int e = blockIdx.x * 256 + threadIdx.x;
    if (e >= E_TOT) return;
    const int d = (e < N_EDGES) ? ei[N_EDGES + e] : (e - N_EDGES);
    atomicAdd(&deg[d], 1);
}

__global__ __launch_bounds__(256) void k_scan_a(const int* __restrict__ deg, int* __restrict__ bsum)
{
    __shared__ int sd[256];
    const int b = blockIdx.x, t = threadIdx.x;
    const int base = b * 1024 + t * 4;
    int s = 0;
#pragma unroll
    for (int i = 0; i < 4; ++i) { const int idx = base + i; if (idx < N_NODES) s += deg[idx]; }
    sd[t] = s; __syncthreads();
    for (int off = 128; off > 0; off >>= 1) {
        if (t < off) sd[t] += sd[t + off];
        __syncthreads();
    }
    if (t == 0) bsum[b] = sd[0];
}

__global__ void k_scan_b(const int* __restrict__ bsum, int* __restrict__ bscan)
{
    if (threadIdx.x == 0) {
        int run = 0;
        for (int i = 0; i < SCAN_NB; ++i) { bscan[i] = run; run += bsum[i]; }
    }
}

__global__ __launch_bounds__(256) void k_scan_c(const int* __restrict__ deg,
                                                const int* __restrict__ bscan,
                                                int* __restrict__ row_ptr,
                                                int* __restrict__ cursor)
{
    __shared__ int sd[256];
    const int b = blockIdx.x, t = threadIdx.x;
    const int base = b * 1024 + t * 4;
    int v0 = 0, v1 = 0, v2 = 0, v3 = 0;
    if (base + 0 < N_NODES) v0 = deg[base + 0];
    if (base + 1 < N_NODES) v1 = deg[base + 1];
    if (base + 2 < N_NODES) v2 = deg[base + 2];
    if (base + 3 < N_NODES) v3 = deg[base + 3];
    const int tot = v0 + v1 + v2 + v3;
    sd[t] = tot; __syncthreads();
    for (int off = 1; off < 256; off <<= 1) {
        int xv = 0;
        if (t >= off) xv = sd[t - off];
        __syncthreads();
        if (t >= off) sd[t] += xv;
        __syncthreads();
    }
    int run = bscan[b] + sd[t] - tot;   // exclusive prefix for this thread
    if (base + 0 < N_NODES) { row_ptr[base + 0] = run; cursor[base + 0] = run; run += v0; }
    if (base + 1 < N_NODES) { row_ptr[base + 1] = run; cursor[base + 1] = run; run += v1; }
    if (base + 2 < N_NODES) { row_ptr[base + 2] = run; cursor[base + 2] = run; run += v2; }
    if (base + 3 < N_NODES) { row_ptr[base + 3] = run; cursor[base + 3] = run; run += v3; }
    if (b == 0 && t == 0) row_ptr[N_NODES] = E_TOT;
}

__global__ __launch_bounds__(256) void k_fill(const int* __restrict__ ei,
                                              int* __restrict__ cursor,
                                              int* __restrict__ col_src)
{
    const int e = blockIdx.x * 256 + threadIdx.x;
    if (e >= E_TOT) return;
    int s, d;
    if (e < N_EDGES) { s = ei[e]; d = ei[N_EDGES + e]; }
    else { s = d = e - N_EDGES; }
    const int pos = atomicAdd(&cursor[d], 1);
    col_src[pos] = s;
}

// ---------------- agg1: GAT layer-1 aggregation + bias + ELU -> x2[N,128] ----------------
__global__ __launch_bounds__(64) void k_agg1(const float* __restrict__ h,
                                             const float* __restrict__ as_,
                                             const float* __restrict__ ad_,
                                             const int* __restrict__ row_ptr,
                                             const int* __restrict__ col_src,
                                             const float* __restrict__ bias,
                                             float* __restrict__ x2)
{
    __shared__ float sEx[256];
    __shared__ int sSrc[64];
    const int n = blockIdx.x;
    const int lane = threadIdx.x;
    const int start = row_ptr[n], end = row_ptr[n + 1];
    const float4 adv = *(const float4*)(ad_ + (size_t)n * 4);

    // pass A: per-head max over incoming edges
    float4 mx = make_float4(-1e30f, -1e30f, -1e30f, -1e30f);
    for (int base = start; base < end; base += 64) {
        const int e = base + lane;
        if (e < end) {
            const float4 av = *(const float4*)(as_ + (size_t)col_src[e] * 4);
            mx.x = fmaxf(mx.x, lrelu(av.x + adv.x));
            mx.y = fmaxf(mx.y, lrelu(av.y + adv.y));
            mx.z = fmaxf(mx.z, lrelu(av.z + adv.z));
            mx.w = fmaxf(mx.w, lrelu(av.w + adv.w));
        }
    }
#pragma unroll
    for (int off = 32; off > 0; off >>= 1) {
        mx.x = fmaxf(mx.x, __shfl_xor(mx.x, off));
        mx.y = fmaxf(mx.y, __shfl_xor(mx.y, off));
        mx.z = fmaxf(mx.z, __shfl_xor(mx.z, off));
        mx.w = fmaxf(mx.w, __shfl_xor(mx.w, off));
    }

    // pass B: weighted gather-accumulate (unnormalized) + denom
    const int hsel = lane >> 4;       // head of this lane's 2 channels
    const int c0 = lane * 2;
    float2 acc = make_float2(0.f, 0.f);
    float4 ds = make_float4(0.f, 0.f, 0.f, 0.f);
    for (int base = start; base < end; base += 64) {
        const int e = base + lane;
        const int cnt = min(64, end - base);
        float4 ex = make_float4(0.f, 0.f, 0.f, 0.f);
        int s = 0;
        if (e < end) {
            s = col_src[e];
            const float4 av = *(const float4*)(as_ + (size_t)s * 4);
            ex.x = __expf(lrelu(av.x + adv.x) - mx.x);
            ex.y = __expf(lrelu(av.y + adv.y) - mx.y);
            ex.z = __expf(lrelu(av.z + adv.z) - mx.z);
            ex.w = __expf(lrelu(av.w + adv.w) - mx.w);
            ds.x += ex.x; ds.y += ex.y; ds.z += ex.z; ds.w += ex.w;
        }
        __syncthreads();
        *(float4*)(sEx + lane * 4) = ex;
        sSrc[lane] = s;
        __syncthreads();
        for (int i = 0; i < cnt; ++i) {
            const float w = sEx[i * 4 + hsel];
            const float2 hv = *(const float2*)(h + (size_t)sSrc[i] * 128 + c0);
            acc.x = fmaf(w, hv.x, acc.x);
            acc.y = fmaf(w, hv.y, acc.y);
        }
    }
#pragma unroll
    for (int off = 32; off > 0; off >>= 1) {
        ds.x += __shfl_xor(ds.x, off);
        ds.y += __shfl_xor(ds.y, off);
        ds.z += __shfl_xor(ds.z, off);
        ds.w += __shfl_xor(ds.w, off);
    }
    const float denom = hsel == 0 ? ds.x : hsel == 1 ? ds.y : hsel == 2 ? ds.z : ds.w;
    float o0 = acc.x / denom + bias[c0];
    float o1 = acc.y / denom + bias[c0 + 1];
    o0 = o0 > 0.f ? o0 : __expf(o0) - 1.f;   // ELU
    o1 = o1 > 0.f ? o1 : __expf(o1) - 1.f;
    *(float2*)(x2 + (size_t)n * 128 + c0) = make_float2(o0, o1);
}

// ---------------- GEMM2: h2[N,32] = x2[N,128] @ W2[128,32], fused alpha2 ----------------
// block = 256 threads = 8 rows x 32 cols; W2 (16KB) in LDS; one scalar acc/thread.
__global__ __launch_bounds__(256) void k_gemm2(const float* __restrict__ x2,
                                               const float* __restrict__ W,
                                               const float* __restrict__ a_src,
                                               const float* __restrict__ a_dst,
                                               float* __restrict__ h2,
                                               float* __restrict__ as_,
                                               float* __restrict__ ad_)
{
    __shared__ float sW[128 * 32];
    const int t = threadIdx.x;
    {
        const float4* W4 = (const float4*)W;
        float4* s4 = (float4*)sW;
#pragma unroll
        for (int i = 0; i < 4; ++i) s4[t + 256 * i] = W4[t + 256 * i];
    }
    __syncthreads();

    const int rr = t >> 5;            // 0..7
    const int c = t & 31;
    const int row = blockIdx.x * 8 + rr;   // 12500 blocks * 8 = 100000 exact
    const float* xp = x2 + (size_t)row * 128;

    float acc = 0.f;
    for (int k = 0; k < 128; k += 4) {
        const float4 xv = *(const float4*)(xp + k);
        acc = fmaf(xv.x, sW[(k + 0) * 32 + c], acc);
        acc = fmaf(xv.y, sW[(k + 1) * 32 + c], acc);
        acc = fmaf(xv.z, sW[(k + 2) * 32 + c], acc);
        acc = fmaf(xv.w, sW[(k + 3) * 32 + c], acc);
    }

    h2[(size_t)row * 32 + c] = acc;
    float ps = acc * a_src[c], pd = acc * a_dst[c];
#pragma unroll
    for (int off = 16; off > 0; off >>= 1) {
        ps += __shfl_xor(ps, off);
        pd += __shfl_xor(pd, off);
    }
    if (c == 0) { as_[row] = ps; ad_[row] = pd; }
}

// ---------------- agg2: GAT layer-2 aggregation + bias -> out[N,32] ----------------
__global__ __launch_bounds__(64) void k_agg2(const float* __restrict__ h,
                                             const float* __restrict__ as_,
                                             const float* __restrict__ ad_,
                                             const int* __restrict__ row_ptr,
                                             const int* __restrict__ col_src,
                                             const float* __restrict__ bias,
                                             float* __restrict__ out)
{
    __shared__ float sEx[64];
    __shared__ int sSrc[64];
    const int n = blockIdx.x;
    const int lane = threadIdx.x;
    const int start = row_ptr[n], end = row_ptr[n + 1];
    const float adn = ad_[n];

    float mx = -1e30f;
    for (int base = start; base < end; base += 64) {
        const int e = base + lane;
        if (e < end) mx = fmaxf(mx, lrelu(as_[col_src[e]] + adn));
    }
#pragma unroll
    for (int off = 32; off > 0; off >>= 1) mx = fmaxf(mx, __shfl_xor(mx, off));

    const int c = lane & 31, half = lane >> 5;
    float acc = 0.f, dsum = 0.f;
    for (int base = start; base < end; base += 64) {
        const int e = base + lane;
        const int cnt = min(64, end - base);
        float ex = 0.f; int s = 0;
        if (e < end) {
            s = col_src[e];
            ex = __expf(lrelu(as_[s] + adn) - mx);
            dsum += ex;
        }
        __syncthreads();
        sEx[lane] = ex;
        sSrc[lane] = s;
        __syncthreads();
        for (int i = half; i < cnt; i += 2)
            acc = fmaf(sEx[i], h[(size_t)sSrc[i] * 32 + c], acc);
    }
#pragma unroll
    for (int off = 32; off > 0; off >>= 1) dsum += __shfl_xor(dsum, off);
    acc += __shfl_xor(acc, 32);
    if (half == 0) out[(size_t)n * 32 + c] = acc / dsum + bias[c];
}

extern "C" void kernel_launch(void* const* d_in, const int* in_sizes, int n_in,
                              void* d_out, int out_size, void* d_ws, size_t ws_size,
                              hipStream_t stream)
{
    const float* x      = (const float*)d_in[0];
    const int*   ei     = (const int*)d_in[1];
    const float* W1     = (const float*)d_in[2];
    const float* a_src1 = (const float*)d_in[3];
    const float* a_dst1 = (const float*)d_in[4];
    const float* b1     = (const float*)d_in[5];
    const float* W2     = (const float*)d_in[6];
    const float* a_src2 = (const float*)d_in[7];
    const float* a_dst2 = (const float*)d_in[8];
    const float* b2     = (const float*)d_in[9];
    float* out = (float*)d_out;

    char* p = (char*)d_ws;
    auto alloc = [&](size_t bytes) { char* q = p; p += (bytes + 255) & ~(size_t)255; return q; };
    float* h1    = (float*)alloc((size_t)N_NODES * 128 * 4);
    float* x2    = (float*)alloc((size_t)N_NODES * 128 * 4);
    float* h2    = (float*)alloc((size_t)N_NODES * 32 * 4);
    float* as1   = (float*)alloc((size_t)N_NODES * 4 * 4);
    float* ad1   = (float*)alloc((size_t)N_NODES * 4 * 4);
    float* as2   = (float*)alloc((size_t)N_NODES * 4);
    float* ad2   = (float*)alloc((size_t)N_NODES * 4);
    int* deg     = (int*)alloc((size_t)N_NODES * 4);
    int* row_ptr = (int*)alloc((size_t)(N_NODES + 1) * 4);
    int* cursor  = (int*)alloc((size_t)N_NODES * 4);
    int* bsum    = (int*)alloc(SCAN_NB * 4);
    int* bscan   = (int*)alloc(SCAN_NB * 4);
    int* col_src = (int*)alloc((size_t)E_TOT * 4);

    hipMemsetAsync(deg, 0, (size_t)N_NODES * 4, stream);

    k_gemm1<<<N_NODES / 16, 256, 0, stream>>>(x, W1, a_src1, a_dst1, h1, as1, ad1);
    k_hist<<<(E_TOT + 255) / 256, 256, 0, stream>>>(ei, deg);
    k_scan_a<<<SCAN_NB, 256, 0, stream>>>(deg, bsum);
    k_scan_b<<<1, 64, 0, stream>>>(bsum, bscan);
    k_scan_c<<<SCAN_NB, 256, 0, stream>>>(deg, bscan, row_ptr, cursor);
    k_fill<<<(E_TOT + 255) / 256, 256, 0, stream>>>(ei, cursor, col_src);
    k_agg1<<<N_NODES, 64, 0, stream>>>(h1, as1, ad1, row_ptr, col_src, b1, x2);
    k_gemm2<<<(N_NODES + 7) / 8, 256, 0, stream>>>(x2, W2, a_src2, a_dst2, h2, as2, ad2);
    k_agg2<<<N_NODES, 64, 0, stream>>>(h2, as2, ad2, row_ptr, col_src, b2, out);
}

// Round 3
// 513.647 us; speedup vs baseline: 2.1477x; 1.1572x over previous
//
#include <hip/hip_runtime.h>
#include <hip/hip_bf16.h>
#include <math.h>

#define N_NODES 100000
#define N_EDGES 1600000
#define E_TOT   1700000   // edges + self loops
#define NEG_SLOPE 0.2f
#define SCAN_NB 98        // ceil(100000/1024)

__device__ __forceinline__ float lrelu(float v) { return v > 0.f ? v : NEG_SLOPE * v; }

// ---------------- GEMM1: h1[N,128] = x[N,128] @ W1[128,128], fused alpha1 ----------------
// block = 256 threads, 64 rows. x-tile staged TRANSPOSED in LDS (one barrier), W from L2.
// thread = (rr = t>>5: 8 rows, cc = t&31: 4 cols) -> 32-FMA micro-tile per k.
__global__ __launch_bounds__(256) void k_gemm1(const float* __restrict__ x,
                                               const float* __restrict__ W,
                                               const float* __restrict__ a_src,
                                               const float* __restrict__ a_dst,
                                               float* __restrict__ h,
                                               float* __restrict__ as_,
                                               float* __restrict__ ad_)
{
    __shared__ float xT[128][64];   // 32 KB, k-major (transposed x tile)
    const int t = threadIdx.x;
    const int row0 = blockIdx.x * 64;

    // stage: thread loads row (t&63), col-chunk (t>>6)*32, writes transposed.
    {
        const int r = t & 63;
        const int c8 = (t >> 6) * 32;
        int rload = row0 + r;
        if (rload > N_NODES - 1) rload = N_NODES - 1;
        const float* xp = x + (size_t)rload * 128 + c8;
#pragma unroll
        for (int j = 0; j < 8; ++j) {
            const float4 v = *(const float4*)(xp + j * 4);
            const int k = c8 + j * 4;
            xT[k + 0][r] = v.x;
            xT[k + 1][r] = v.y;
            xT[k + 2][r] = v.z;
            xT[k + 3][r] = v.w;
        }
    }
    __syncthreads();

    const int cc = t & 31;
    const int rr = t >> 5;
    const int c0 = cc * 4;
    const int r0 = rr * 8;

    float4 acc[8];
#pragma unroll
    for (int i = 0; i < 8; ++i) acc[i] = make_float4(0.f, 0.f, 0.f, 0.f);

#pragma unroll 4
    for (int k = 0; k < 128; ++k) {
        const float4 w = *(const float4*)(W + k * 128 + c0);
        const float4 xa = *(const float4*)(&xT[k][r0]);
        const float4 xb = *(const float4*)(&xT[k][r0 + 4]);
        acc[0].x = fmaf(xa.x, w.x, acc[0].x); acc[0].y = fmaf(xa.x, w.y, acc[0].y);
        acc[0].z = fmaf(xa.x, w.z, acc[0].z); acc[0].w = fmaf(xa.x, w.w, acc[0].w);
        acc[1].x = fmaf(xa.y, w.x, acc[1].x); acc[1].y = fmaf(xa.y, w.y, acc[1].y);
        acc[1].z = fmaf(xa.y, w.z, acc[1].z); acc[1].w = fmaf(xa.y, w.w, acc[1].w);
        acc[2].x = fmaf(xa.z, w.x, acc[2].x); acc[2].y = fmaf(xa.z, w.y, acc[2].y);
        acc[2].z = fmaf(xa.z, w.z, acc[2].z); acc[2].w = fmaf(xa.z, w.w, acc[2].w);
        acc[3].x = fmaf(xa.w, w.x, acc[3].x); acc[3].y = fmaf(xa.w, w.y, acc[3].y);
        acc[3].z = fmaf(xa.w, w.z, acc[3].z); acc[3].w = fmaf(xa.w, w.w, acc[3].w);
        acc[4].x = fmaf(xb.x, w.x, acc[4].x); acc[4].y = fmaf(xb.x, w.y, acc[4].y);
        acc[4].z = fmaf(xb.x, w.z, acc[4].z); acc[4].w = fmaf(xb.x, w.w, acc[4].w);
        acc[5].x = fmaf(xb.y, w.x, acc[5].x); acc[5].y = fmaf(xb.y, w.y, acc[5].y);
        acc[5].z = fmaf(xb.y, w.z, acc[5].z); acc[5].w = fmaf(xb.y, w.w, acc[5].w);
        acc[6].x = fmaf(xb.z, w.x, acc[6].x); acc[6].y = fmaf(xb.z, w.y, acc[6].y);
        acc[6].z = fmaf(xb.z, w.z, acc[6].z); acc[6].w = fmaf(xb.z, w.w, acc[6].w);
        acc[7].x = fmaf(xb.w, w.x, acc[7].x); acc[7].y = fmaf(xb.w, w.y, acc[7].y);
        acc[7].z = fmaf(xb.w, w.z, acc[7].z); acc[7].w = fmaf(xb.w, w.w, acc[7].w);
    }

    // epilogue: write h1 + fused alpha dot-products. head = cc>>3 (8 lanes per head).
    const float4 av = *(const float4*)(a_src + c0);
    const float4 bv = *(const float4*)(a_dst + c0);
    const int head = cc >> 3;
#pragma unroll
    for (int i = 0; i < 8; ++i) {
        const int r = row0 + r0 + i;
        float ps = acc[i].x * av.x + acc[i].y * av.y + acc[i].z * av.z + acc[i].w * av.w;
        float pd = acc[i].x * bv.x + acc[i].y * bv.y + acc[i].z * bv.z + acc[i].w * bv.w;
        ps += __shfl_xor(ps, 1); pd += __shfl_xor(pd, 1);
        ps += __shfl_xor(ps, 2); pd += __shfl_xor(pd, 2);
        ps += __shfl_xor(ps, 4); pd += __shfl_xor(pd, 4);
        if (r < N_NODES) {
            *(float4*)(h + (size_t)r * 128 + c0) = acc[i];
            if ((cc & 7) == 0) { as_[r * 4 + head] = ps; ad_[r * 4 + head] = pd; }
        }
    }
}

// ---------------- CSR build ----------------
__global__ __launch_bounds__(256) void k_hist(const int* __restrict__ ei, int* __restrict__ deg)
{
    const int e = blockIdx.x * 256 + threadIdx.x;
    if (e >= E_TOT) return;
    const int d = (e < N_EDGES) ? ei[N_EDGES + e] : (e - N_EDGES);
    atomicAdd(&deg[d], 1);
}

__global__ __launch_bounds__(256) void k_scan_a(const int* __restrict__ deg, int* __restrict__ bsum)
{
    __shared__ int sd[256];
    const int b = blockIdx.x, t = threadIdx.x;
    const int base = b * 1024 + t * 4;
    int s = 0;
#pragma unroll
    for (int i = 0; i < 4; ++i) { const int idx = base + i; if (idx < N_NODES) s += deg[idx]; }
    sd[t] = s; __syncthreads();
    for (int off = 128; off > 0; off >>= 1) {
        if (t < off) sd[t] += sd[t + off];
        __syncthreads();
    }
    if (t == 0) bsum[b] = sd[0];
}

__global__ void k_scan_b(const int* __restrict__ bsum, int* __restrict__ bscan)
{
    if (threadIdx.x == 0) {
        int run = 0;
        for (int i = 0; i < SCAN_NB; ++i) { bscan[i] = run; run += bsum[i]; }
    }
}

__global__ __launch_bounds__(256) void k_scan_c(const int* __restrict__ deg,
                                                const int* __restrict__ bscan,
                                                int* __restrict__ row_ptr,
                                                int* __restrict__ cursor)
{
    __shared__ int sd[256];
    const int b = blockIdx.x, t = threadIdx.x;
    const int base = b * 1024 + t * 4;
    int v0 = 0, v1 = 0, v2 = 0, v3 = 0;
    if (base + 0 < N_NODES) v0 = deg[base + 0];
    if (base + 1 < N_NODES) v1 = deg[base + 1];
    if (base + 2 < N_NODES) v2 = deg[base + 2];
    if (base + 3 < N_NODES) v3 = deg[base + 3];
    const int tot = v0 + v1 + v2 + v3;
    sd[t] = tot; __syncthreads();
    for (int off = 1; off < 256; off <<= 1) {
        int xv = 0;
        if (t >= off) xv = sd[t - off];
        __syncthreads();
        if (t >= off) sd[t] += xv;
        __syncthreads();
    }
    int run = bscan[b] + sd[t] - tot;   // exclusive prefix for this thread
    if (base + 0 < N_NODES) { row_ptr[base + 0] = run; cursor[base + 0] = run; run += v0; }
    if (base + 1 < N_NODES) { row_ptr[base + 1] = run; cursor[base + 1] = run; run += v1; }
    if (base + 2 < N_NODES) { row_ptr[base + 2] = run; cursor[base + 2] = run; run += v2; }
    if (base + 3 < N_NODES) { row_ptr[base + 3] = run; cursor[base + 3] = run; run += v3; }
    if (b == 0 && t == 0) row_ptr[N_NODES] = E_TOT;
}

__global__ __launch_bounds__(256) void k_fill(const int* __restrict__ ei,
                                              int* __restrict__ cursor,
                                              int* __restrict__ col_src)
{
    const int e = blockIdx.x * 256 + threadIdx.x;
    if (e >= E_TOT) return;
    int s, d;
    if (e < N_EDGES) { s = ei[e]; d = ei[N_EDGES + e]; }
    else { s = d = e - N_EDGES; }
    const int pos = atomicAdd(&cursor[d], 1);
    col_src[pos] = s;
}

// ---------------- agg1: GAT layer-1 aggregation + bias + ELU -> x2[N,128] ----------------
__global__ __launch_bounds__(64) void k_agg1(const float* __restrict__ h,
                                             const float* __restrict__ as_,
                                             const float* __restrict__ ad_,
                                             const int* __restrict__ row_ptr,
                                             const int* __restrict__ col_src,
                                             const float* __restrict__ bias,
                                             float* __restrict__ x2)
{
    __shared__ float sEx[256];
    __shared__ int sSrc[64];
    const int n = blockIdx.x;
    const int lane = threadIdx.x;
    const int start = row_ptr[n], end = row_ptr[n + 1];
    const float4 adv = *(const float4*)(ad_ + (size_t)n * 4);

    // pass A: per-head max over incoming edges
    float4 mx = make_float4(-1e30f, -1e30f, -1e30f, -1e30f);
    for (int base = start; base < end; base += 64) {
        const int e = base + lane;
        if (e < end) {
            const float4 av = *(const float4*)(as_ + (size_t)col_src[e] * 4);
            mx.x = fmaxf(mx.x, lrelu(av.x + adv.x));
            mx.y = fmaxf(mx.y, lrelu(av.y + adv.y));
            mx.z = fmaxf(mx.z, lrelu(av.z + adv.z));
            mx.w = fmaxf(mx.w, lrelu(av.w + adv.w));
        }
    }
#pragma unroll
    for (int off = 32; off > 0; off >>= 1) {
        mx.x = fmaxf(mx.x, __shfl_xor(mx.x, off));
        mx.y = fmaxf(mx.y, __shfl_xor(mx.y, off));
        mx.z = fmaxf(mx.z, __shfl_xor(mx.z, off));
        mx.w = fmaxf(mx.w, __shfl_xor(mx.w, off));
    }

    // pass B: weighted gather-accumulate (unnormalized) + denom
    const int hsel = lane >> 4;       // head of this lane's 2 channels
    const int c0 = lane * 2;
    float2 acc = make_float2(0.f, 0.f);
    float4 ds = make_float4(0.f, 0.f, 0.f, 0.f);
    for (int base = start; base < end; base += 64) {
        const int e = base + lane;
        const int cnt = min(64, end - base);
        float4 ex = make_float4(0.f, 0.f, 0.f, 0.f);
        int s = 0;
        if (e < end) {
            s = col_src[e];
            const float4 av = *(const float4*)(as_ + (size_t)s * 4);
            ex.x = __expf(lrelu(av.x + adv.x) - mx.x);
            ex.y = __expf(lrelu(av.y + adv.y) - mx.y);
            ex.z = __expf(lrelu(av.z + adv.z) - mx.z);
            ex.w = __expf(lrelu(av.w + adv.w) - mx.w);
            ds.x += ex.x; ds.y += ex.y; ds.z += ex.z; ds.w += ex.w;
        }
        __syncthreads();
        *(float4*)(sEx + lane * 4) = ex;
        sSrc[lane] = s;
        __syncthreads();
        for (int i = 0; i < cnt; ++i) {
            const float w = sEx[i * 4 + hsel];
            const float2 hv = *(const float2*)(h + (size_t)sSrc[i] * 128 + c0);
            acc.x = fmaf(w, hv.x, acc.x);
            acc.y = fmaf(w, hv.y, acc.y);
        }
    }
#pragma unroll
    for (int off = 32; off > 0; off >>= 1) {
        ds.x += __shfl_xor(ds.x, off);
        ds.y += __shfl_xor(ds.y, off);
        ds.z += __shfl_xor(ds.z, off);
        ds.w += __shfl_xor(ds.w, off);
    }
    const float denom = hsel == 0 ? ds.x : hsel == 1 ? ds.y : hsel == 2 ? ds.z : ds.w;
    float o0 = acc.x / denom + bias[c0];
    float o1 = acc.y / denom + bias[c0 + 1];
    o0 = o0 > 0.f ? o0 : __expf(o0) - 1.f;   // ELU
    o1 = o1 > 0.f ? o1 : __expf(o1) - 1.f;
    *(float2*)(x2 + (size_t)n * 128 + c0) = make_float2(o0, o1);
}

// ---------------- GEMM2: h2[N,32] = x2[N,128] @ W2[128,32], fused alpha2 ----------------
// block = 256 threads = 8 rows x 32 cols; W2 (16KB) in LDS; one scalar acc/thread.
__global__ __launch_bounds__(256) void k_gemm2(const float* __restrict__ x2,
                                               const float* __restrict__ W,
                                               const float* __restrict__ a_src,
                                               const float* __restrict__ a_dst,
                                               float* __restrict__ h2,
                                               float* __restrict__ as_,
                                               float* __restrict__ ad_)
{
    __shared__ float sW[128 * 32];
    const int t = threadIdx.x;
    {
        const float4* W4 = (const float4*)W;
        float4* s4 = (float4*)sW;
#pragma unroll
        for (int i = 0; i < 4; ++i) s4[t + 256 * i] = W4[t + 256 * i];
    }
    __syncthreads();

    const int rr = t >> 5;            // 0..7
    const int c = t & 31;
    const int row = blockIdx.x * 8 + rr;   // 12500 blocks * 8 = 100000 exact
    const float* xp = x2 + (size_t)row * 128;

    float acc = 0.f;
    for (int k = 0; k < 128; k += 4) {
        const float4 xv = *(const float4*)(xp + k);
        acc = fmaf(xv.x, sW[(k + 0) * 32 + c], acc);
        acc = fmaf(xv.y, sW[(k + 1) * 32 + c], acc);
        acc = fmaf(xv.z, sW[(k + 2) * 32 + c], acc);
        acc = fmaf(xv.w, sW[(k + 3) * 32 + c], acc);
    }

    h2[(size_t)row * 32 + c] = acc;
    float ps = acc * a_src[c], pd = acc * a_dst[c];
#pragma unroll
    for (int off = 16; off > 0; off >>= 1) {
        ps += __shfl_xor(ps, off);
        pd += __shfl_xor(pd, off);
    }
    if (c == 0) { as_[row] = ps; ad_[row] = pd; }
}

// ---------------- agg2: GAT layer-2 aggregation + bias -> out[N,32] ----------------
__global__ __launch_bounds__(64) void k_agg2(const float* __restrict__ h,
                                             const float* __restrict__ as_,
                                             const float* __restrict__ ad_,
                                             const int* __restrict__ row_ptr,
                                             const int* __restrict__ col_src,
                                             const float* __restrict__ bias,
                                             float* __restrict__ out)
{
    __shared__ float sEx[64];
    __shared__ int sSrc[64];
    const int n = blockIdx.x;
    const int lane = threadIdx.x;
    const int start = row_ptr[n], end = row_ptr[n + 1];
    const float adn = ad_[n];

    float mx = -1e30f;
    for (int base = start; base < end; base += 64) {
        const int e = base + lane;
        if (e < end) mx = fmaxf(mx, lrelu(as_[col_src[e]] + adn));
    }
#pragma unroll
    for (int off = 32; off > 0; off >>= 1) mx = fmaxf(mx, __shfl_xor(mx, off));

    const int c = lane & 31, half = lane >> 5;
    float acc = 0.f, dsum = 0.f;
    for (int base = start; base < end; base += 64) {
        const int e = base + lane;
        const int cnt = min(64, end - base);
        float ex = 0.f; int s = 0;
        if (e < end) {
            s = col_src[e];
            ex = __expf(lrelu(as_[s] + adn) - mx);
            dsum += ex;
        }
        __syncthreads();
        sEx[lane] = ex;
        sSrc[lane] = s;
        __syncthreads();
        for (int i = half; i < cnt; i += 2)
            acc = fmaf(sEx[i], h[(size_t)sSrc[i] * 32 + c], acc);
    }
#pragma unroll
    for (int off = 32; off > 0; off >>= 1) dsum += __shfl_xor(dsum, off);
    acc += __shfl_xor(acc, 32);
    if (half == 0) out[(size_t)n * 32 + c] = acc / dsum + bias[c];
}

extern "C" void kernel_launch(void* const* d_in, const int* in_sizes, int n_in,
                              void* d_out, int out_size, void* d_ws, size_t ws_size,
                              hipStream_t stream)
{
    const float* x      = (const float*)d_in[0];
    const int*   ei     = (const int*)d_in[1];
    const float* W1     = (const float*)d_in[2];
    const float* a_src1 = (const float*)d_in[3];
    const float* a_dst1 = (const float*)d_in[4];
    const float* b1     = (const float*)d_in[5];
    const float* W2     = (const float*)d_in[6];
    const float* a_src2 = (const float*)d_in[7];
    const float* a_dst2 = (const float*)d_in[8];
    const float* b2     = (const float*)d_in[9];
    float* out = (float*)d_out;

    char* p = (char*)d_ws;
    auto alloc = [&](size_t bytes) { char* q = p; p += (bytes + 255) & ~(size_t)255; return q; };
    float* h1    = (float*)alloc((size_t)N_NODES * 128 * 4);
    float* x2    = (float*)alloc((size_t)N_NODES * 128 * 4);
    float* h2    = (float*)alloc((size_t)N_NODES * 32 * 4);
    float* as1   = (float*)alloc((size_t)N_NODES * 4 * 4);
    float* ad1   = (float*)alloc((size_t)N_NODES * 4 * 4);
    float* as2   = (float*)alloc((size_t)N_NODES * 4);
    float* ad2   = (float*)alloc((size_t)N_NODES * 4);
    int* deg     = (int*)alloc((size_t)N_NODES * 4);
    int* row_ptr = (int*)alloc((size_t)(N_NODES + 1) * 4);
    int* cursor  = (int*)alloc((size_t)N_NODES * 4);
    int* bsum    = (int*)alloc(SCAN_NB * 4);
    int* bscan   = (int*)alloc(SCAN_NB * 4);
    int* col_src = (int*)alloc((size_t)E_TOT * 4);

    hipMemsetAsync(deg, 0, (size_t)N_NODES * 4, stream);

    k_gemm1<<<(N_NODES + 63) / 64, 256, 0, stream>>>(x, W1, a_src1, a_dst1, h1, as1, ad1);
    k_hist<<<(E_TOT + 255) / 256, 256, 0, stream>>>(ei, deg);
    k_scan_a<<<SCAN_NB, 256, 0, stream>>>(deg, bsum);
    k_scan_b<<<1, 64, 0, stream>>>(bsum, bscan);
    k_scan_c<<<SCAN_NB, 256, 0, stream>>>(deg, bscan, row_ptr, cursor);
    k_fill<<<(E_TOT + 255) / 256, 256, 0, stream>>>(ei, cursor, col_src);
    k_agg1<<<N_NODES, 64, 0, stream>>>(h1, as1, ad1, row_ptr, col_src, b1, x2);
    k_gemm2<<<(N_NODES + 7) / 8, 256, 0, stream>>>(x2, W2, a_src2, a_dst2, h2, as2, ad2);
    k_agg2<<<N_NODES, 64, 0, stream>>>(h2, as2, ad2, row_ptr, col_src, b2, out);
}

// Round 5
// 457.184 us; speedup vs baseline: 2.4130x; 1.1235x over previous
//
#include <hip/hip_runtime.h>
#include <math.h>

#define N_NODES 100000
#define N_EDGES 1600000
#define E_TOT   1700000   // edges + self loops
#define NEG_SLOPE 0.2f
#define SCAN_NB 98        // ceil(100000/1024)

typedef unsigned short ushort_t;
typedef unsigned int uint_t;

__device__ __forceinline__ float lrelu(float v) { return v > 0.f ? v : NEG_SLOPE * v; }
__device__ __forceinline__ float bf16lo(uint_t u) { return __uint_as_float(u << 16); }
__device__ __forceinline__ float bf16hi(uint_t u) { return __uint_as_float(u & 0xffff0000u); }
// f32 -> bf16 with round-to-nearest-even (bit arithmetic, no type dependency)
__device__ __forceinline__ ushort_t f2bf(float f) {
    uint_t u = __float_as_uint(f);
    u += 0x7fffu + ((u >> 16) & 1u);
    return (ushort_t)(u >> 16);
}

// ---------------- GEMM1: h1[N,128](bf16) = x[N,128] @ W1[128,128], fused alpha1 ----------------
// block = 256 threads, 64 rows. x-tile staged TRANSPOSED in LDS (one barrier), W from L2.
__global__ __launch_bounds__(256) void k_gemm1(const float* __restrict__ x,
                                               const float* __restrict__ W,
                                               const float* __restrict__ a_src,
                                               const float* __restrict__ a_dst,
                                               ushort_t* __restrict__ hb,
                                               float* __restrict__ as_,
                                               float* __restrict__ ad_)
{
    __shared__ float xT[128][64];   // 32 KB, k-major (transposed x tile)
    const int t = threadIdx.x;
    const int row0 = blockIdx.x * 64;

    {
        const int r = t & 63;
        const int c8 = (t >> 6) * 32;
        int rload = row0 + r;
        if (rload > N_NODES - 1) rload = N_NODES - 1;
        const float* xp = x + (size_t)rload * 128 + c8;
#pragma unroll
        for (int j = 0; j < 8; ++j) {
            const float4 v = *(const float4*)(xp + j * 4);
            const int k = c8 + j * 4;
            xT[k + 0][r] = v.x;
            xT[k + 1][r] = v.y;
            xT[k + 2][r] = v.z;
            xT[k + 3][r] = v.w;
        }
    }
    __syncthreads();

    const int cc = t & 31;
    const int rr = t >> 5;
    const int c0 = cc * 4;
    const int r0 = rr * 8;

    float4 acc[8];
#pragma unroll
    for (int i = 0; i < 8; ++i) acc[i] = make_float4(0.f, 0.f, 0.f, 0.f);

#pragma unroll 4
    for (int k = 0; k < 128; ++k) {
        const float4 w = *(const float4*)(W + k * 128 + c0);
        const float4 xa = *(const float4*)(&xT[k][r0]);
        const float4 xb = *(const float4*)(&xT[k][r0 + 4]);
        acc[0].x = fmaf(xa.x, w.x, acc[0].x); acc[0].y = fmaf(xa.x, w.y, acc[0].y);
        acc[0].z = fmaf(xa.x, w.z, acc[0].z); acc[0].w = fmaf(xa.x, w.w, acc[0].w);
        acc[1].x = fmaf(xa.y, w.x, acc[1].x); acc[1].y = fmaf(xa.y, w.y, acc[1].y);
        acc[1].z = fmaf(xa.y, w.z, acc[1].z); acc[1].w = fmaf(xa.y, w.w, acc[1].w);
        acc[2].x = fmaf(xa.z, w.x, acc[2].x); acc[2].y = fmaf(xa.z, w.y, acc[2].y);
        acc[2].z = fmaf(xa.z, w.z, acc[2].z); acc[2].w = fmaf(xa.z, w.w, acc[2].w);
        acc[3].x = fmaf(xa.w, w.x, acc[3].x); acc[3].y = fmaf(xa.w, w.y, acc[3].y);
        acc[3].z = fmaf(xa.w, w.z, acc[3].z); acc[3].w = fmaf(xa.w, w.w, acc[3].w);
        acc[4].x = fmaf(xb.x, w.x, acc[4].x); acc[4].y = fmaf(xb.x, w.y, acc[4].y);
        acc[4].z = fmaf(xb.x, w.z, acc[4].z); acc[4].w = fmaf(xb.x, w.w, acc[4].w);
        acc[5].x = fmaf(xb.y, w.x, acc[5].x); acc[5].y = fmaf(xb.y, w.y, acc[5].y);
        acc[5].z = fmaf(xb.y, w.z, acc[5].z); acc[5].w = fmaf(xb.y, w.w, acc[5].w);
        acc[6].x = fmaf(xb.z, w.x, acc[6].x); acc[6].y = fmaf(xb.z, w.y, acc[6].y);
        acc[6].z = fmaf(xb.z, w.z, acc[6].z); acc[6].w = fmaf(xb.z, w.w, acc[6].w);
        acc[7].x = fmaf(xb.w, w.x, acc[7].x); acc[7].y = fmaf(xb.w, w.y, acc[7].y);
        acc[7].z = fmaf(xb.w, w.z, acc[7].z); acc[7].w = fmaf(xb.w, w.w, acc[7].w);
    }

    const float4 av = *(const float4*)(a_src + c0);
    const float4 bv = *(const float4*)(a_dst + c0);
    const int head = cc >> 3;
#pragma unroll
    for (int i = 0; i < 8; ++i) {
        const int r = row0 + r0 + i;
        float ps = acc[i].x * av.x + acc[i].y * av.y + acc[i].z * av.z + acc[i].w * av.w;
        float pd = acc[i].x * bv.x + acc[i].y * bv.y + acc[i].z * bv.z + acc[i].w * bv.w;
        ps += __shfl_xor(ps, 1); pd += __shfl_xor(pd, 1);
        ps += __shfl_xor(ps, 2); pd += __shfl_xor(pd, 2);
        ps += __shfl_xor(ps, 4); pd += __shfl_xor(pd, 4);
        if (r < N_NODES) {
            // pack 4 floats -> 4 bf16 (8 B store)
            const uint_t p0 = f2bf(acc[i].x), p1 = f2bf(acc[i].y);
            const uint_t p2 = f2bf(acc[i].z), p3 = f2bf(acc[i].w);
            uint2 packed = make_uint2(p0 | (p1 << 16), p2 | (p3 << 16));
            *(uint2*)(hb + (size_t)r * 128 + c0) = packed;
            if ((cc & 7) == 0) { as_[r * 4 + head] = ps; ad_[r * 4 + head] = pd; }
        }
    }
}

// ---------------- CSR build ----------------
__global__ __launch_bounds__(256) void k_hist(const int* __restrict__ ei, int* __restrict__ deg)
{
    const int e = blockIdx.x * 256 + threadIdx.x;
    if (e >= E_TOT) return;
    const int d = (e < N_EDGES) ? ei[N_EDGES + e] : (e - N_EDGES);
    atomicAdd(&deg[d], 1);
}

__global__ __launch_bounds__(256) void k_scan_a(const int* __restrict__ deg, int* __restrict__ bsum)
{
    __shared__ int sd[256];
    const int b = blockIdx.x, t = threadIdx.x;
    const int base = b * 1024 + t * 4;
    int s = 0;
#pragma unroll
    for (int i = 0; i < 4; ++i) { const int idx = base + i; if (idx < N_NODES) s += deg[idx]; }
    sd[t] = s; __syncthreads();
    for (int off = 128; off > 0; off >>= 1) {
        if (t < off) sd[t] += sd[t + off];
        __syncthreads();
    }
    if (t == 0) bsum[b] = sd[0];
}

__global__ void k_scan_b(const int* __restrict__ bsum, int* __restrict__ bscan)
{
    if (threadIdx.x == 0) {
        int run = 0;
        for (int i = 0; i < SCAN_NB; ++i) { bscan[i] = run; run += bsum[i]; }
    }
}

__global__ __launch_bounds__(256) void k_scan_c(const int* __restrict__ deg,
                                                const int* __restrict__ bscan,
                                                int* __restrict__ row_ptr,
                                                int* __restrict__ cursor)
{
    __shared__ int sd[256];
    const int b = blockIdx.x, t = threadIdx.x;
    const int base = b * 1024 + t * 4;
    int v0 = 0, v1 = 0, v2 = 0, v3 = 0;
    if (base + 0 < N_NODES) v0 = deg[base + 0];
    if (base + 1 < N_NODES) v1 = deg[base + 1];
    if (base + 2 < N_NODES) v2 = deg[base + 2];
    if (base + 3 < N_NODES) v3 = deg[base + 3];
    const int tot = v0 + v1 + v2 + v3;
    sd[t] = tot; __syncthreads();
    for (int off = 1; off < 256; off <<= 1) {
        int xv = 0;
        if (t >= off) xv = sd[t - off];
        __syncthreads();
        if (t >= off) sd[t] += xv;
        __syncthreads();
    }
    int run = bscan[b] + sd[t] - tot;
    if (base + 0 < N_NODES) { row_ptr[base + 0] = run; cursor[base + 0] = run; run += v0; }
    if (base + 1 < N_NODES) { row_ptr[base + 1] = run; cursor[base + 1] = run; run += v1; }
    if (base + 2 < N_NODES) { row_ptr[base + 2] = run; cursor[base + 2] = run; run += v2; }
    if (base + 3 < N_NODES) { row_ptr[base + 3] = run; cursor[base + 3] = run; run += v3; }
    if (b == 0 && t == 0) row_ptr[N_NODES] = E_TOT;
}

__global__ __launch_bounds__(256) void k_fill(const int* __restrict__ ei,
                                              int* __restrict__ cursor,
                                              int* __restrict__ col_src)
{
    const int e = blockIdx.x * 256 + threadIdx.x;
    if (e >= E_TOT) return;
    int s, d;
    if (e < N_EDGES) { s = ei[e]; d = ei[N_EDGES + e]; }
    else { s = d = e - N_EDGES; }
    const int pos = atomicAdd(&cursor[d], 1);
    col_src[pos] = s;
}

// ---------------- agg1: layer-1 aggregation + bias + ELU -> x2[N,128] (f32) ----------------
// h gathered as bf16 (256 B/row); first-chunk logits cached in registers.
__global__ __launch_bounds__(64) void k_agg1(const ushort_t* __restrict__ hb,
                                             const float* __restrict__ as_,
                                             const float* __restrict__ ad_,
                                             const int* __restrict__ row_ptr,
                                             const int* __restrict__ col_src,
                                             const float* __restrict__ bias,
                                             float* __restrict__ x2)
{
    __shared__ float sEx[256];
    __shared__ int sSrc[64];
    const int n = blockIdx.x;
    const int lane = threadIdx.x;
    const int start = row_ptr[n], end = row_ptr[n + 1];
    const float4 adv = *(const float4*)(ad_ + (size_t)n * 4);

    // pass A: per-head max; cache first chunk's logits + src
    float4 mx = make_float4(-1e30f, -1e30f, -1e30f, -1e30f);
    float4 lgc = make_float4(0.f, 0.f, 0.f, 0.f);
    int sc = 0;
    for (int base = start; base < end; base += 64) {
        const int e = base + lane;
        if (e < end) {
            const int s = col_src[e];
            const float4 av = *(const float4*)(as_ + (size_t)s * 4);
            float4 lg;
            lg.x = lrelu(av.x + adv.x);
            lg.y = lrelu(av.y + adv.y);
            lg.z = lrelu(av.z + adv.z);
            lg.w = lrelu(av.w + adv.w);
            if (base == start) { lgc = lg; sc = s; }
            mx.x = fmaxf(mx.x, lg.x);
            mx.y = fmaxf(mx.y, lg.y);
            mx.z = fmaxf(mx.z, lg.z);
            mx.w = fmaxf(mx.w, lg.w);
        }
    }
#pragma unroll
    for (int off = 32; off > 0; off >>= 1) {
        mx.x = fmaxf(mx.x, __shfl_xor(mx.x, off));
        mx.y = fmaxf(mx.y, __shfl_xor(mx.y, off));
        mx.z = fmaxf(mx.z, __shfl_xor(mx.z, off));
        mx.w = fmaxf(mx.w, __shfl_xor(mx.w, off));
    }

    // pass B: weighted gather-accumulate (unnormalized) + denom
    const int hsel = lane >> 4;
    const int c0 = lane * 2;
    float2 acc = make_float2(0.f, 0.f);
    float4 ds = make_float4(0.f, 0.f, 0.f, 0.f);
    for (int base = start; base < end; base += 64) {
        const int e = base + lane;
        const int cnt = min(64, end - base);
        float4 ex = make_float4(0.f, 0.f, 0.f, 0.f);
        int s = 0;
        if (e < end) {
            float4 lg;
            if (base == start) { s = sc; lg = lgc; }
            else {
                s = col_src[e];
                const float4 av = *(const float4*)(as_ + (size_t)s * 4);
                lg.x = lrelu(av.x + adv.x);
                lg.y = lrelu(av.y + adv.y);
                lg.z = lrelu(av.z + adv.z);
                lg.w = lrelu(av.w + adv.w);
            }
            ex.x = __expf(lg.x - mx.x);
            ex.y = __expf(lg.y - mx.y);
            ex.z = __expf(lg.z - mx.z);
            ex.w = __expf(lg.w - mx.w);
            ds.x += ex.x; ds.y += ex.y; ds.z += ex.z; ds.w += ex.w;
        }
        __syncthreads();
        *(float4*)(sEx + lane * 4) = ex;
        sSrc[lane] = s;
        __syncthreads();
        for (int i = 0; i < cnt; ++i) {
            const float w = sEx[i * 4 + hsel];
            const uint_t hv = *(const uint_t*)(hb + (size_t)sSrc[i] * 128 + c0);
            acc.x = fmaf(w, bf16lo(hv), acc.x);
            acc.y = fmaf(w, bf16hi(hv), acc.y);
        }
    }
#pragma unroll
    for (int off = 32; off > 0; off >>= 1) {
        ds.x += __shfl_xor(ds.x, off);
        ds.y += __shfl_xor(ds.y, off);
        ds.z += __shfl_xor(ds.z, off);
        ds.w += __shfl_xor(ds.w, off);
    }
    const float denom = hsel == 0 ? ds.x : hsel == 1 ? ds.y : hsel == 2 ? ds.z : ds.w;
    float o0 = acc.x / denom + bias[c0];
    float o1 = acc.y / denom + bias[c0 + 1];
    o0 = o0 > 0.f ? o0 : __expf(o0) - 1.f;   // ELU
    o1 = o1 > 0.f ? o1 : __expf(o1) - 1.f;
    *(float2*)(x2 + (size_t)n * 128 + c0) = make_float2(o0, o1);
}

// ---------------- GEMM2: h2[N,32](bf16) = x2[N,128] @ W2[128,32], fused alpha2 ----------------
__global__ __launch_bounds__(256) void k_gemm2(const float* __restrict__ x2,
                                               const float* __restrict__ W,
                                               const float* __restrict__ a_src,
                                               const float* __restrict__ a_dst,
                                               ushort_t* __restrict__ hb2,
                                               float* __restrict__ as_,
                                               float* __restrict__ ad_)
{
    __shared__ float sW[128 * 32];
    const int t = threadIdx.x;
    {
        const float4* W4 = (const float4*)W;
        float4* s4 = (float4*)sW;
#pragma unroll
        for (int i = 0; i < 4; ++i) s4[t + 256 * i] = W4[t + 256 * i];
    }
    __syncthreads();

    const int rr = t >> 5;
    const int c = t & 31;
    const int row = blockIdx.x * 8 + rr;
    const float* xp = x2 + (size_t)row * 128;

    float acc = 0.f;
    for (int k = 0; k < 128; k += 4) {
        const float4 xv = *(const float4*)(xp + k);
        acc = fmaf(xv.x, sW[(k + 0) * 32 + c], acc);
        acc = fmaf(xv.y, sW[(k + 1) * 32 + c], acc);
        acc = fmaf(xv.z, sW[(k + 2) * 32 + c], acc);
        acc = fmaf(xv.w, sW[(k + 3) * 32 + c], acc);
    }

    hb2[(size_t)row * 32 + c] = f2bf(acc);
    float ps = acc * a_src[c], pd = acc * a_dst[c];
#pragma unroll
    for (int off = 16; off > 0; off >>= 1) {
        ps += __shfl_xor(ps, off);
        pd += __shfl_xor(pd, off);
    }
    if (c == 0) { as_[row] = ps; ad_[row] = pd; }
}

// ---------------- agg2: layer-2 aggregation + bias -> out[N,32] ----------------
__global__ __launch_bounds__(64) void k_agg2(const ushort_t* __restrict__ hb2,
                                             const float* __restrict__ as_,
                                             const float* __restrict__ ad_,
                                             const int* __restrict__ row_ptr,
                                             const int* __restrict__ col_src,
                                             const float* __restrict__ bias,
                                             float* __restrict__ out)
{
    __shared__ float sEx[64];
    __shared__ int sSrc[64];
    const int n = blockIdx.x;
    const int lane = threadIdx.x;
    const int start = row_ptr[n], end = row_ptr[n + 1];
    const float adn = ad_[n];

    float mx = -1e30f;
    float lgc = 0.f;
    int sc = 0;
    for (int base = start; base < end; base += 64) {
        const int e = base + lane;
        if (e < end) {
            const int s = col_src[e];
            const float lg = lrelu(as_[s] + adn);
            if (base == start) { lgc = lg; sc = s; }
            mx = fmaxf(mx, lg);
        }
    }
#pragma unroll
    for (int off = 32; off > 0; off >>= 1) mx = fmaxf(mx, __shfl_xor(mx, off));

    const int c = lane & 31, half = lane >> 5;
    float acc = 0.f, dsum = 0.f;
    for (int base = start; base < end; base += 64) {
        const int e = base + lane;
        const int cnt = min(64, end - base);
        float ex = 0.f; int s = 0;
        if (e < end) {
            float lg;
            if (base == start) { s = sc; lg = lgc; }
            else { s = col_src[e]; lg = lrelu(as_[s] + adn); }
            ex = __expf(lg - mx);
            dsum += ex;
        }
        __syncthreads();
        sEx[lane] = ex;
        sSrc[lane] = s;
        __syncthreads();
        for (int i = half; i < cnt; i += 2) {
            const ushort_t u = hb2[(size_t)sSrc[i] * 32 + c];
            acc = fmaf(sEx[i], __uint_as_float((uint_t)u << 16), acc);
        }
    }
#pragma unroll
    for (int off = 32; off > 0; off >>= 1) dsum += __shfl_xor(dsum, off);
    acc += __shfl_xor(acc, 32);
    if (half == 0) out[(size_t)n * 32 + c] = acc / dsum + bias[c];
}

extern "C" void kernel_launch(void* const* d_in, const int* in_sizes, int n_in,
                              void* d_out, int out_size, void* d_ws, size_t ws_size,
                              hipStream_t stream)
{
    const float* x      = (const float*)d_in[0];
    const int*   ei     = (const int*)d_in[1];
    const float* W1     = (const float*)d_in[2];
    const float* a_src1 = (const float*)d_in[3];
    const float* a_dst1 = (const float*)d_in[4];
    const float* b1     = (const float*)d_in[5];
    const float* W2     = (const float*)d_in[6];
    const float* a_src2 = (const float*)d_in[7];
    const float* a_dst2 = (const float*)d_in[8];
    const float* b2     = (const float*)d_in[9];
    float* out = (float*)d_out;

    char* p = (char*)d_ws;
    auto alloc = [&](size_t bytes) { char* q = p; p += (bytes + 255) & ~(size_t)255; return q; };
    ushort_t* h1b = (ushort_t*)alloc((size_t)N_NODES * 128 * 2);
    float* x2     = (float*)alloc((size_t)N_NODES * 128 * 4);
    ushort_t* h2b = (ushort_t*)alloc((size_t)N_NODES * 32 * 2);
    float* as1    = (float*)alloc((size_t)N_NODES * 4 * 4);
    float* ad1    = (float*)alloc((size_t)N_NODES * 4 * 4);
    float* as2    = (float*)alloc((size_t)N_NODES * 4);
    float* ad2    = (float*)alloc((size_t)N_NODES * 4);
    int* deg      = (int*)alloc((size_t)N_NODES * 4);
    int* row_ptr  = (int*)alloc((size_t)(N_NODES + 1) * 4);
    int* cursor   = (int*)alloc((size_t)N_NODES * 4);
    int* bsum     = (int*)alloc(SCAN_NB * 4);
    int* bscan    = (int*)alloc(SCAN_NB * 4);
    int* col_src  = (int*)alloc((size_t)E_TOT * 4);

    (void)hipMemsetAsync(deg, 0, (size_t)N_NODES * 4, stream);

    k_gemm1<<<(N_NODES + 63) / 64, 256, 0, stream>>>(x, W1, a_src1, a_dst1, h1b, as1, ad1);
    k_hist<<<(E_TOT + 255) / 256, 256, 0, stream>>>(ei, deg);
    k_scan_a<<<SCAN_NB, 256, 0, stream>>>(deg, bsum);
    k_scan_b<<<1, 64, 0, stream>>>(bsum, bscan);
    k_scan_c<<<SCAN_NB, 256, 0, stream>>>(deg, bscan, row_ptr, cursor);
    k_fill<<<(E_TOT + 255) / 256, 256, 0, stream>>>(ei, cursor, col_src);
    k_agg1<<<N_NODES, 64, 0, stream>>>(h1b, as1, ad1, row_ptr, col_src, b1, x2);
    k_gemm2<<<(N_NODES + 7) / 8, 256, 0, stream>>>(x2, W2, a_src2, a_dst2, h2b, as2, ad2);
    k_agg2<<<N_NODES, 64, 0, stream>>>(h2b, as2, ad2, row_ptr, col_src, b2, out);
}

// Round 6
// 364.097 us; speedup vs baseline: 3.0299x; 1.2557x over previous
//
#include <hip/hip_runtime.h>
#include <math.h>

#define N_NODES 100000
#define N_EDGES 1600000
#define E_TOT   1700000   // edges + self loops
#define NEG_SLOPE 0.2f
#define SCAN_NB 98        // ceil(100000/1024)

typedef unsigned short ushort_t;
typedef unsigned int uint_t;

__device__ __forceinline__ float lrelu(float v) { return v > 0.f ? v : NEG_SLOPE * v; }
__device__ __forceinline__ float bf16lo(uint_t u) { return __uint_as_float(u << 16); }
__device__ __forceinline__ float bf16hi(uint_t u) { return __uint_as_float(u & 0xffff0000u); }
// f32 -> bf16 with round-to-nearest-even (bit arithmetic, no type dependency)
__device__ __forceinline__ ushort_t f2bf(float f) {
    uint_t u = __float_as_uint(f);
    u += 0x7fffu + ((u >> 16) & 1u);
    return (ushort_t)(u >> 16);
}

// ---------------- GEMM1: h1[N,128](bf16) = x[N,128] @ W1[128,128], fused alpha1 ----------------
__global__ __launch_bounds__(256) void k_gemm1(const float* __restrict__ x,
                                               const float* __restrict__ W,
                                               const float* __restrict__ a_src,
                                               const float* __restrict__ a_dst,
                                               ushort_t* __restrict__ hb,
                                               float* __restrict__ as_,
                                               float* __restrict__ ad_)
{
    __shared__ float xT[128][64];   // 32 KB, k-major (transposed x tile)
    const int t = threadIdx.x;
    const int row0 = blockIdx.x * 64;

    {
        const int r = t & 63;
        const int c8 = (t >> 6) * 32;
        int rload = row0 + r;
        if (rload > N_NODES - 1) rload = N_NODES - 1;
        const float* xp = x + (size_t)rload * 128 + c8;
#pragma unroll
        for (int j = 0; j < 8; ++j) {
            const float4 v = *(const float4*)(xp + j * 4);
            const int k = c8 + j * 4;
            xT[k + 0][r] = v.x;
            xT[k + 1][r] = v.y;
            xT[k + 2][r] = v.z;
            xT[k + 3][r] = v.w;
        }
    }
    __syncthreads();

    const int cc = t & 31;
    const int rr = t >> 5;
    const int c0 = cc * 4;
    const int r0 = rr * 8;

    float4 acc[8];
#pragma unroll
    for (int i = 0; i < 8; ++i) acc[i] = make_float4(0.f, 0.f, 0.f, 0.f);

#pragma unroll 4
    for (int k = 0; k < 128; ++k) {
        const float4 w = *(const float4*)(W + k * 128 + c0);
        const float4 xa = *(const float4*)(&xT[k][r0]);
        const float4 xb = *(const float4*)(&xT[k][r0 + 4]);
        acc[0].x = fmaf(xa.x, w.x, acc[0].x); acc[0].y = fmaf(xa.x, w.y, acc[0].y);
        acc[0].z = fmaf(xa.x, w.z, acc[0].z); acc[0].w = fmaf(xa.x, w.w, acc[0].w);
        acc[1].x = fmaf(xa.y, w.x, acc[1].x); acc[1].y = fmaf(xa.y, w.y, acc[1].y);
        acc[1].z = fmaf(xa.y, w.z, acc[1].z); acc[1].w = fmaf(xa.y, w.w, acc[1].w);
        acc[2].x = fmaf(xa.z, w.x, acc[2].x); acc[2].y = fmaf(xa.z, w.y, acc[2].y);
        acc[2].z = fmaf(xa.z, w.z, acc[2].z); acc[2].w = fmaf(xa.z, w.w, acc[2].w);
        acc[3].x = fmaf(xa.w, w.x, acc[3].x); acc[3].y = fmaf(xa.w, w.y, acc[3].y);
        acc[3].z = fmaf(xa.w, w.z, acc[3].z); acc[3].w = fmaf(xa.w, w.w, acc[3].w);
        acc[4].x = fmaf(xb.x, w.x, acc[4].x); acc[4].y = fmaf(xb.x, w.y, acc[4].y);
        acc[4].z = fmaf(xb.x, w.z, acc[4].z); acc[4].w = fmaf(xb.x, w.w, acc[4].w);
        acc[5].x = fmaf(xb.y, w.x, acc[5].x); acc[5].y = fmaf(xb.y, w.y, acc[5].y);
        acc[5].z = fmaf(xb.y, w.z, acc[5].z); acc[5].w = fmaf(xb.y, w.w, acc[5].w);
        acc[6].x = fmaf(xb.z, w.x, acc[6].x); acc[6].y = fmaf(xb.z, w.y, acc[6].y);
        acc[6].z = fmaf(xb.z, w.z, acc[6].z); acc[6].w = fmaf(xb.z, w.w, acc[6].w);
        acc[7].x = fmaf(xb.w, w.x, acc[7].x); acc[7].y = fmaf(xb.w, w.y, acc[7].y);
        acc[7].z = fmaf(xb.w, w.z, acc[7].z); acc[7].w = fmaf(xb.w, w.w, acc[7].w);
    }

    const float4 av = *(const float4*)(a_src + c0);
    const float4 bv = *(const float4*)(a_dst + c0);
    const int head = cc >> 3;
#pragma unroll
    for (int i = 0; i < 8; ++i) {
        const int r = row0 + r0 + i;
        float ps = acc[i].x * av.x + acc[i].y * av.y + acc[i].z * av.z + acc[i].w * av.w;
        float pd = acc[i].x * bv.x + acc[i].y * bv.y + acc[i].z * bv.z + acc[i].w * bv.w;
        ps += __shfl_xor(ps, 1); pd += __shfl_xor(pd, 1);
        ps += __shfl_xor(ps, 2); pd += __shfl_xor(pd, 2);
        ps += __shfl_xor(ps, 4); pd += __shfl_xor(pd, 4);
        if (r < N_NODES) {
            const uint_t p0 = f2bf(acc[i].x), p1 = f2bf(acc[i].y);
            const uint_t p2 = f2bf(acc[i].z), p3 = f2bf(acc[i].w);
            uint2 packed = make_uint2(p0 | (p1 << 16), p2 | (p3 << 16));
            *(uint2*)(hb + (size_t)r * 128 + c0) = packed;
            if ((cc & 7) == 0) { as_[r * 4 + head] = ps; ad_[r * 4 + head] = pd; }
        }
    }
}

// ---------------- CSR build ----------------
// hist also records each edge's within-row rank (returned by the atomic).
__global__ __launch_bounds__(256) void k_hist(const int* __restrict__ ei,
                                              int* __restrict__ deg,
                                              int* __restrict__ rank)
{
    const int e = blockIdx.x * 256 + threadIdx.x;
    if (e >= E_TOT) return;
    const int d = (e < N_EDGES) ? ei[N_EDGES + e] : (e - N_EDGES);
    rank[e] = atomicAdd(&deg[d], 1);
}

__global__ __launch_bounds__(256) void k_scan_a(const int* __restrict__ deg, int* __restrict__ bsum)
{
    __shared__ int sd[256];
    const int b = blockIdx.x, t = threadIdx.x;
    const int base = b * 1024 + t * 4;
    int s = 0;
#pragma unroll
    for (int i = 0; i < 4; ++i) { const int idx = base + i; if (idx < N_NODES) s += deg[idx]; }
    sd[t] = s; __syncthreads();
    for (int off = 128; off > 0; off >>= 1) {
        if (t < off) sd[t] += sd[t + off];
        __syncthreads();
    }
    if (t == 0) bsum[b] = sd[0];
}

__global__ void k_scan_b(const int* __restrict__ bsum, int* __restrict__ bscan)
{
    if (threadIdx.x == 0) {
        int run = 0;
        for (int i = 0; i < SCAN_NB; ++i) { bscan[i] = run; run += bsum[i]; }
    }
}

__global__ __launch_bounds__(256) void k_scan_c(const int* __restrict__ deg,
                                                const int* __restrict__ bscan,
                                                int* __restrict__ row_ptr)
{
    __shared__ int sd[256];
    const int b = blockIdx.x, t = threadIdx.x;
    const int base = b * 1024 + t * 4;
    int v0 = 0, v1 = 0, v2 = 0, v3 = 0;
    if (base + 0 < N_NODES) v0 = deg[base + 0];
    if (base + 1 < N_NODES) v1 = deg[base + 1];
    if (base + 2 < N_NODES) v2 = deg[base + 2];
    if (base + 3 < N_NODES) v3 = deg[base + 3];
    const int tot = v0 + v1 + v2 + v3;
    sd[t] = tot; __syncthreads();
    for (int off = 1; off < 256; off <<= 1) {
        int xv = 0;
        if (t >= off) xv = sd[t - off];
        __syncthreads();
        if (t >= off) sd[t] += xv;
        __syncthreads();
    }
    int run = bscan[b] + sd[t] - tot;
    if (base + 0 < N_NODES) { row_ptr[base + 0] = run; run += v0; }
    if (base + 1 < N_NODES) { row_ptr[base + 1] = run; run += v1; }
    if (base + 2 < N_NODES) { row_ptr[base + 2] = run; run += v2; }
    if (base + 3 < N_NODES) { row_ptr[base + 3] = run; run += v3; }
    if (b == 0 && t == 0) row_ptr[N_NODES] = E_TOT;
}

// atomic-free fill: position = row_ptr[d] + rank[e]; store is fire-and-forget.
__global__ __launch_bounds__(256) void k_fill(const int* __restrict__ ei,
                                              const int* __restrict__ row_ptr,
                                              const int* __restrict__ rank,
                                              int* __restrict__ col_src)
{
    const int e = blockIdx.x * 256 + threadIdx.x;
    if (e >= E_TOT) return;
    int s, d;
    if (e < N_EDGES) { s = ei[e]; d = ei[N_EDGES + e]; }
    else { s = d = e - N_EDGES; }
    col_src[row_ptr[d] + rank[e]] = s;
}

// ---------------- agg1: layer-1 aggregation + bias + ELU -> x2[N,128] (f32) ----------------
__global__ __launch_bounds__(64) void k_agg1(const ushort_t* __restrict__ hb,
                                             const float* __restrict__ as_,
                                             const float* __restrict__ ad_,
                                             const int* __restrict__ row_ptr,
                                             const int* __restrict__ col_src,
                                             const float* __restrict__ bias,
                                             float* __restrict__ x2)
{
    __shared__ float sEx[256];
    __shared__ int sSrc[64];
    const int n = blockIdx.x;
    const int lane = threadIdx.x;
    const int start = row_ptr[n], end = row_ptr[n + 1];
    const float4 adv = *(const float4*)(ad_ + (size_t)n * 4);

    // pass A: per-head max; cache first chunk's logits + src
    float4 mx = make_float4(-1e30f, -1e30f, -1e30f, -1e30f);
    float4 lgc = make_float4(0.f, 0.f, 0.f, 0.f);
    int sc = 0;
    for (int base = start; base < end; base += 64) {
        const int e = base + lane;
        if (e < end) {
            const int s = col_src[e];
            const float4 av = *(const float4*)(as_ + (size_t)s * 4);
            float4 lg;
            lg.x = lrelu(av.x + adv.x);
            lg.y = lrelu(av.y + adv.y);
            lg.z = lrelu(av.z + adv.z);
            lg.w = lrelu(av.w + adv.w);
            if (base == start) { lgc = lg; sc = s; }
            mx.x = fmaxf(mx.x, lg.x);
            mx.y = fmaxf(mx.y, lg.y);
            mx.z = fmaxf(mx.z, lg.z);
            mx.w = fmaxf(mx.w, lg.w);
        }
    }
#pragma unroll
    for (int off = 32; off > 0; off >>= 1) {
        mx.x = fmaxf(mx.x, __shfl_xor(mx.x, off));
        mx.y = fmaxf(mx.y, __shfl_xor(mx.y, off));
        mx.z = fmaxf(mx.z, __shfl_xor(mx.z, off));
        mx.w = fmaxf(mx.w, __shfl_xor(mx.w, off));
    }

    // pass B: weighted gather-accumulate (unnormalized) + denom
    const int hsel = lane >> 4;
    const int c0 = lane * 2;
    float2 acc = make_float2(0.f, 0.f);
    float4 ds = make_float4(0.f, 0.f, 0.f, 0.f);
    for (int base = start; base < end; base += 64) {
        const int e = base + lane;
        const int cnt = min(64, end - base);
        float4 ex = make_float4(0.f, 0.f, 0.f, 0.f);
        int s = 0;
        if (e < end) {
            float4 lg;
            if (base == start) { s = sc; lg = lgc; }
            else {
                s = col_src[e];
                const float4 av = *(const float4*)(as_ + (size_t)s * 4);
                lg.x = lrelu(av.x + adv.x);
                lg.y = lrelu(av.y + adv.y);
                lg.z = lrelu(av.z + adv.z);
                lg.w = lrelu(av.w + adv.w);
            }
            ex.x = __expf(lg.x - mx.x);
            ex.y = __expf(lg.y - mx.y);
            ex.z = __expf(lg.z - mx.z);
            ex.w = __expf(lg.w - mx.w);
            ds.x += ex.x; ds.y += ex.y; ds.z += ex.z; ds.w += ex.w;
        }
        __syncthreads();
        *(float4*)(sEx + lane * 4) = ex;
        sSrc[lane] = s;
        __syncthreads();
        for (int i = 0; i < cnt; ++i) {
            const float w = sEx[i * 4 + hsel];
            const uint_t hv = *(const uint_t*)(hb + (size_t)sSrc[i] * 128 + c0);
            acc.x = fmaf(w, bf16lo(hv), acc.x);
            acc.y = fmaf(w, bf16hi(hv), acc.y);
        }
    }
#pragma unroll
    for (int off = 32; off > 0; off >>= 1) {
        ds.x += __shfl_xor(ds.x, off);
        ds.y += __shfl_xor(ds.y, off);
        ds.z += __shfl_xor(ds.z, off);
        ds.w += __shfl_xor(ds.w, off);
    }
    const float denom = hsel == 0 ? ds.x : hsel == 1 ? ds.y : hsel == 2 ? ds.z : ds.w;
    float o0 = acc.x / denom + bias[c0];
    float o1 = acc.y / denom + bias[c0 + 1];
    o0 = o0 > 0.f ? o0 : __expf(o0) - 1.f;   // ELU
    o1 = o1 > 0.f ? o1 : __expf(o1) - 1.f;
    *(float2*)(x2 + (size_t)n * 128 + c0) = make_float2(o0, o1);
}

// ---------------- GEMM2: h2[N,32](bf16) = x2[N,128] @ W2[128,32], fused alpha2 ----------------
__global__ __launch_bounds__(256) void k_gemm2(const float* __restrict__ x2,
                                               const float* __restrict__ W,
                                               const float* __restrict__ a_src,
                                               const float* __restrict__ a_dst,
                                               ushort_t* __restrict__ hb2,
                                               float* __restrict__ as_,
                                               float* __restrict__ ad_)
{
    __shared__ float sW[128 * 32];
    const int t = threadIdx.x;
    {
        const float4* W4 = (const float4*)W;
        float4* s4 = (float4*)sW;
#pragma unroll
        for (int i = 0; i < 4; ++i) s4[t + 256 * i] = W4[t + 256 * i];
    }
    __syncthreads();

    const int rr = t >> 5;
    const int c = t & 31;
    const int row = blockIdx.x * 8 + rr;
    const float* xp = x2 + (size_t)row * 128;

    float acc = 0.f;
    for (int k = 0; k < 128; k += 4) {
        const float4 xv = *(const float4*)(xp + k);
        acc = fmaf(xv.x, sW[(k + 0) * 32 + c], acc);
        acc = fmaf(xv.y, sW[(k + 1) * 32 + c], acc);
        acc = fmaf(xv.z, sW[(k + 2) * 32 + c], acc);
        acc = fmaf(xv.w, sW[(k + 3) * 32 + c], acc);
    }

    hb2[(size_t)row * 32 + c] = f2bf(acc);
    float ps = acc * a_src[c], pd = acc * a_dst[c];
#pragma unroll
    for (int off = 16; off > 0; off >>= 1) {
        ps += __shfl_xor(ps, off);
        pd += __shfl_xor(pd, off);
    }
    if (c == 0) { as_[row] = ps; ad_[row] = pd; }
}

// ---------------- agg2: layer-2 aggregation + bias -> out[N,32] ----------------
__global__ __launch_bounds__(64) void k_agg2(const ushort_t* __restrict__ hb2,
                                             const float* __restrict__ as_,
                                             const float* __restrict__ ad_,
                                             const int* __restrict__ row_ptr,
                                             const int* __restrict__ col_src,
                                             const float* __restrict__ bias,
                                             float* __restrict__ out)
{
    __shared__ float sEx[64];
    __shared__ int sSrc[64];
    const int n = blockIdx.x;
    const int lane = threadIdx.x;
    const int start = row_ptr[n], end = row_ptr[n + 1];
    const float adn = ad_[n];

    float mx = -1e30f;
    float lgc = 0.f;
    int sc = 0;
    for (int base = start; base < end; base += 64) {
        const int e = base + lane;
        if (e < end) {
            const int s = col_src[e];
            const float lg = lrelu(as_[s] + adn);
            if (base == start) { lgc = lg; sc = s; }
            mx = fmaxf(mx, lg);
        }
    }
#pragma unroll
    for (int off = 32; off > 0; off >>= 1) mx = fmaxf(mx, __shfl_xor(mx, off));

    const int c = lane & 31, half = lane >> 5;
    float acc = 0.f, dsum = 0.f;
    for (int base = start; base < end; base += 64) {
        const int e = base + lane;
        const int cnt = min(64, end - base);
        float ex = 0.f; int s = 0;
        if (e < end) {
            float lg;
            if (base == start) { s = sc; lg = lgc; }
            else { s = col_src[e]; lg = lrelu(as_[s] + adn); }
            ex = __expf(lg - mx);
            dsum += ex;
        }
        __syncthreads();
        sEx[lane] = ex;
        sSrc[lane] = s;
        __syncthreads();
        for (int i = half; i < cnt; i += 2) {
            const ushort_t u = hb2[(size_t)sSrc[i] * 32 + c];
            acc = fmaf(sEx[i], __uint_as_float((uint_t)u << 16), acc);
        }
    }
#pragma unroll
    for (int off = 32; off > 0; off >>= 1) dsum += __shfl_xor(dsum, off);
    acc += __shfl_xor(acc, 32);
    if (half == 0) out[(size_t)n * 32 + c] = acc / dsum + bias[c];
}

extern "C" void kernel_launch(void* const* d_in, const int* in_sizes, int n_in,
                              void* d_out, int out_size, void* d_ws, size_t ws_size,
                              hipStream_t stream)
{
    const float* x      = (const float*)d_in[0];
    const int*   ei     = (const int*)d_in[1];
    const float* W1     = (const float*)d_in[2];
    const float* a_src1 = (const float*)d_in[3];
    const float* a_dst1 = (const float*)d_in[4];
    const float* b1     = (const float*)d_in[5];
    const float* W2     = (const float*)d_in[6];
    const float* a_src2 = (const float*)d_in[7];
    const float* a_dst2 = (const float*)d_in[8];
    const float* b2     = (const float*)d_in[9];
    float* out = (float*)d_out;

    char* p = (char*)d_ws;
    auto alloc = [&](size_t bytes) { char* q = p; p += (bytes + 255) & ~(size_t)255; return q; };
    ushort_t* h1b = (ushort_t*)alloc((size_t)N_NODES * 128 * 2);
    float* x2     = (float*)alloc((size_t)N_NODES * 128 * 4);
    ushort_t* h2b = (ushort_t*)alloc((size_t)N_NODES * 32 * 2);
    float* as1    = (float*)alloc((size_t)N_NODES * 4 * 4);
    float* ad1    = (float*)alloc((size_t)N_NODES * 4 * 4);
    float* as2    = (float*)alloc((size_t)N_NODES * 4);
    float* ad2    = (float*)alloc((size_t)N_NODES * 4);
    int* deg      = (int*)alloc((size_t)N_NODES * 4);
    int* row_ptr  = (int*)alloc((size_t)(N_NODES + 1) * 4);
    int* rank     = (int*)alloc((size_t)E_TOT * 4);
    int* bsum     = (int*)alloc(SCAN_NB * 4);
    int* bscan    = (int*)alloc(SCAN_NB * 4);
    int* col_src  = (int*)alloc((size_t)E_TOT * 4);

    (void)hipMemsetAsync(deg, 0, (size_t)N_NODES * 4, stream);

    k_gemm1<<<(N_NODES + 63) / 64, 256, 0, stream>>>(x, W1, a_src1, a_dst1, h1b, as1, ad1);
    k_hist<<<(E_TOT + 255) / 256, 256, 0, stream>>>(ei, deg, rank);
    k_scan_a<<<SCAN_NB, 256, 0, stream>>>(deg, bsum);
    k_scan_b<<<1, 64, 0, stream>>>(bsum, bscan);
    k_scan_c<<<SCAN_NB, 256, 0, stream>>>(deg, bscan, row_ptr);
    k_fill<<<(E_TOT + 255) / 256, 256, 0, stream>>>(ei, row_ptr, rank, col_src);
    k_agg1<<<N_NODES, 64, 0, stream>>>(h1b, as1, ad1, row_ptr, col_src, b1, x2);
    k_gemm2<<<(N_NODES + 7) / 8, 256, 0, stream>>>(x2, W2, a_src2, a_dst2, h2b, as2, ad2);
    k_agg2<<<N_NODES, 64, 0, stream>>>(h2b, as2, ad2, row_ptr, col_src, b2, out);
}

// Round 7
// 321.288 us; speedup vs baseline: 3.4336x; 1.1332x over previous
//
#include <hip/hip_runtime.h>
#include <math.h>

#define N_NODES 100000
#define N_EDGES 1600000
#define E_TOT   1700000   // edges + self loops
#define NEG_SLOPE 0.2f
#define SCAN_NB 98        // ceil(100000/1024)
#define G1_BLOCKS 1563    // ceil(100000/64)
#define HIST_BLOCKS 6641  // ceil(1700000/256)

typedef unsigned short ushort_t;
typedef unsigned int uint_t;

__device__ __forceinline__ float lrelu(float v) { return v > 0.f ? v : NEG_SLOPE * v; }
__device__ __forceinline__ float bf16lo(uint_t u) { return __uint_as_float(u << 16); }
__device__ __forceinline__ float bf16hi(uint_t u) { return __uint_as_float(u & 0xffff0000u); }
// f32 -> bf16 round-to-nearest-even
__device__ __forceinline__ ushort_t f2bf(float f) {
    uint_t u = __float_as_uint(f);
    u += 0x7fffu + ((u >> 16) & 1u);
    return (ushort_t)(u >> 16);
}

// ---------------- fused GEMM1 (+alpha1) || hist ----------------
// blocks [0, G1_BLOCKS): h1[N,128](bf16) = x @ W1, fused alpha1 dots.
// blocks [G1_BLOCKS, +HIST_BLOCKS): degree histogram + per-edge rank.
__global__ __launch_bounds__(256) void k_gemm1_hist(const float* __restrict__ x,
                                                    const float* __restrict__ W,
                                                    const float* __restrict__ a_src,
                                                    const float* __restrict__ a_dst,
                                                    ushort_t* __restrict__ hb,
                                                    float* __restrict__ as_,
                                                    float* __restrict__ ad_,
                                                    const int* __restrict__ ei,
                                                    int* __restrict__ deg,
                                                    int* __restrict__ rank)
{
    __shared__ float xT[128][64];   // 32 KB (gemm1 path only)
    const int t = threadIdx.x;

    if (blockIdx.x >= G1_BLOCKS) {
        // ---- hist path ----
        const int e = (blockIdx.x - G1_BLOCKS) * 256 + t;
        if (e < E_TOT) {
            const int d = (e < N_EDGES) ? ei[N_EDGES + e] : (e - N_EDGES);
            rank[e] = atomicAdd(&deg[d], 1);
        }
        return;
    }

    // ---- gemm1 path ----
    const int row0 = blockIdx.x * 64;
    {
        const int r = t & 63;
        const int c8 = (t >> 6) * 32;
        int rload = row0 + r;
        if (rload > N_NODES - 1) rload = N_NODES - 1;
        const float* xp = x + (size_t)rload * 128 + c8;
#pragma unroll
        for (int j = 0; j < 8; ++j) {
            const float4 v = *(const float4*)(xp + j * 4);
            const int k = c8 + j * 4;
            xT[k + 0][r] = v.x;
            xT[k + 1][r] = v.y;
            xT[k + 2][r] = v.z;
            xT[k + 3][r] = v.w;
        }
    }
    __syncthreads();

    const int cc = t & 31;
    const int rr = t >> 5;
    const int c0 = cc * 4;
    const int r0 = rr * 8;

    float4 acc[8];
#pragma unroll
    for (int i = 0; i < 8; ++i) acc[i] = make_float4(0.f, 0.f, 0.f, 0.f);

#pragma unroll 4
    for (int k = 0; k < 128; ++k) {
        const float4 w = *(const float4*)(W + k * 128 + c0);
        const float4 xa = *(const float4*)(&xT[k][r0]);
        const float4 xb = *(const float4*)(&xT[k][r0 + 4]);
        acc[0].x = fmaf(xa.x, w.x, acc[0].x); acc[0].y = fmaf(xa.x, w.y, acc[0].y);
        acc[0].z = fmaf(xa.x, w.z, acc[0].z); acc[0].w = fmaf(xa.x, w.w, acc[0].w);
        acc[1].x = fmaf(xa.y, w.x, acc[1].x); acc[1].y = fmaf(xa.y, w.y, acc[1].y);
        acc[1].z = fmaf(xa.y, w.z, acc[1].z); acc[1].w = fmaf(xa.y, w.w, acc[1].w);
        acc[2].x = fmaf(xa.z, w.x, acc[2].x); acc[2].y = fmaf(xa.z, w.y, acc[2].y);
        acc[2].z = fmaf(xa.z, w.z, acc[2].z); acc[2].w = fmaf(xa.z, w.w, acc[2].w);
        acc[3].x = fmaf(xa.w, w.x, acc[3].x); acc[3].y = fmaf(xa.w, w.y, acc[3].y);
        acc[3].z = fmaf(xa.w, w.z, acc[3].z); acc[3].w = fmaf(xa.w, w.w, acc[3].w);
        acc[4].x = fmaf(xb.x, w.x, acc[4].x); acc[4].y = fmaf(xb.x, w.y, acc[4].y);
        acc[4].z = fmaf(xb.x, w.z, acc[4].z); acc[4].w = fmaf(xb.x, w.w, acc[4].w);
        acc[5].x = fmaf(xb.y, w.x, acc[5].x); acc[5].y = fmaf(xb.y, w.y, acc[5].y);
        acc[5].z = fmaf(xb.y, w.z, acc[5].z); acc[5].w = fmaf(xb.y, w.w, acc[5].w);
        acc[6].x = fmaf(xb.z, w.x, acc[6].x); acc[6].y = fmaf(xb.z, w.y, acc[6].y);
        acc[6].z = fmaf(xb.z, w.z, acc[6].z); acc[6].w = fmaf(xb.z, w.w, acc[6].w);
        acc[7].x = fmaf(xb.w, w.x, acc[7].x); acc[7].y = fmaf(xb.w, w.y, acc[7].y);
        acc[7].z = fmaf(xb.w, w.z, acc[7].z); acc[7].w = fmaf(xb.w, w.w, acc[7].w);
    }

    const float4 av = *(const float4*)(a_src + c0);
    const float4 bv = *(const float4*)(a_dst + c0);
    const int head = cc >> 3;
#pragma unroll
    for (int i = 0; i < 8; ++i) {
        const int r = row0 + r0 + i;
        float ps = acc[i].x * av.x + acc[i].y * av.y + acc[i].z * av.z + acc[i].w * av.w;
        float pd = acc[i].x * bv.x + acc[i].y * bv.y + acc[i].z * bv.z + acc[i].w * bv.w;
        ps += __shfl_xor(ps, 1); pd += __shfl_xor(pd, 1);
        ps += __shfl_xor(ps, 2); pd += __shfl_xor(pd, 2);
        ps += __shfl_xor(ps, 4); pd += __shfl_xor(pd, 4);
        if (r < N_NODES) {
            const uint_t p0 = f2bf(acc[i].x), p1 = f2bf(acc[i].y);
            const uint_t p2 = f2bf(acc[i].z), p3 = f2bf(acc[i].w);
            uint2 packed = make_uint2(p0 | (p1 << 16), p2 | (p3 << 16));
            *(uint2*)(hb + (size_t)r * 128 + c0) = packed;
            if ((cc & 7) == 0) { as_[r * 4 + head] = ps; ad_[r * 4 + head] = pd; }
        }
    }
}

// ---------------- CSR scan ----------------
__global__ __launch_bounds__(256) void k_scan_a(const int* __restrict__ deg, int* __restrict__ bsum)
{
    __shared__ int sd[256];
    const int b = blockIdx.x, t = threadIdx.x;
    const int base = b * 1024 + t * 4;
    int s = 0;
#pragma unroll
    for (int i = 0; i < 4; ++i) { const int idx = base + i; if (idx < N_NODES) s += deg[idx]; }
    sd[t] = s; __syncthreads();
    for (int off = 128; off > 0; off >>= 1) {
        if (t < off) sd[t] += sd[t + off];
        __syncthreads();
    }
    if (t == 0) bsum[b] = sd[0];
}

// scan_c with inlined block-offset reduction (scan_b folded in)
__global__ __launch_bounds__(256) void k_scan_c(const int* __restrict__ deg,
                                                const int* __restrict__ bsum,
                                                int* __restrict__ row_ptr)
{
    __shared__ int sd[256];
    __shared__ int sb[256];
    const int b = blockIdx.x, t = threadIdx.x;

    sb[t] = (t < b && t < SCAN_NB) ? bsum[t] : 0;
    __syncthreads();
    for (int off = 128; off > 0; off >>= 1) {
        if (t < off) sb[t] += sb[t + off];
        __syncthreads();
    }
    const int bscan_b = sb[0];

    const int base = b * 1024 + t * 4;
    int v0 = 0, v1 = 0, v2 = 0, v3 = 0;
    if (base + 0 < N_NODES) v0 = deg[base + 0];
    if (base + 1 < N_NODES) v1 = deg[base + 1];
    if (base + 2 < N_NODES) v2 = deg[base + 2];
    if (base + 3 < N_NODES) v3 = deg[base + 3];
    const int tot = v0 + v1 + v2 + v3;
    sd[t] = tot; __syncthreads();
    for (int off = 1; off < 256; off <<= 1) {
        int xv = 0;
        if (t >= off) xv = sd[t - off];
        __syncthreads();
        if (t >= off) sd[t] += xv;
        __syncthreads();
    }
    int run = bscan_b + sd[t] - tot;
    if (base + 0 < N_NODES) { row_ptr[base + 0] = run; run += v0; }
    if (base + 1 < N_NODES) { row_ptr[base + 1] = run; run += v1; }
    if (base + 2 < N_NODES) { row_ptr[base + 2] = run; run += v2; }
    if (base + 3 < N_NODES) { row_ptr[base + 3] = run; run += v3; }
    if (b == 0 && t == 0) row_ptr[N_NODES] = E_TOT;
}

// atomic-free fill
__global__ __launch_bounds__(256) void k_fill(const int* __restrict__ ei,
                                              const int* __restrict__ row_ptr,
                                              const int* __restrict__ rank,
                                              int* __restrict__ col_src)
{
    const int e = blockIdx.x * 256 + threadIdx.x;
    if (e >= E_TOT) return;
    int s, d;
    if (e < N_EDGES) { s = ei[e]; d = ei[N_EDGES + e]; }
    else { s = d = e - N_EDGES; }
    col_src[row_ptr[d] + rank[e]] = s;
}

// ---------------- agg1: single-pass softmax (no max-sub) + bias + ELU -> x2[N,128] bf16 ----------------
__global__ __launch_bounds__(64) void k_agg1(const ushort_t* __restrict__ hb,
                                             const float* __restrict__ as_,
                                             const float* __restrict__ ad_,
                                             const int* __restrict__ row_ptr,
                                             const int* __restrict__ col_src,
                                             const float* __restrict__ bias,
                                             ushort_t* __restrict__ x2b)
{
    __shared__ float sEx[256];
    __shared__ int sSrc[64];
    const int n = blockIdx.x;
    const int lane = threadIdx.x;
    const int start = row_ptr[n], end = row_ptr[n + 1];
    const float4 adv = *(const float4*)(ad_ + (size_t)n * 4);

    const int hsel = lane >> 4;
    const int c0 = lane * 2;
    float2 acc = make_float2(0.f, 0.f);
    float4 ds = make_float4(0.f, 0.f, 0.f, 0.f);
    for (int base = start; base < end; base += 64) {
        const int e = base + lane;
        const int cnt = min(64, end - base);
        float4 ex = make_float4(0.f, 0.f, 0.f, 0.f);
        int s = 0;
        if (e < end) {
            s = col_src[e];
            const float4 av = *(const float4*)(as_ + (size_t)s * 4);
            ex.x = __expf(lrelu(av.x + adv.x));
            ex.y = __expf(lrelu(av.y + adv.y));
            ex.z = __expf(lrelu(av.z + adv.z));
            ex.w = __expf(lrelu(av.w + adv.w));
            ds.x += ex.x; ds.y += ex.y; ds.z += ex.z; ds.w += ex.w;
        }
        __syncthreads();
        *(float4*)(sEx + lane * 4) = ex;
        sSrc[lane] = s;
        __syncthreads();
        for (int i = 0; i < cnt; ++i) {
            const float w = sEx[i * 4 + hsel];
            const uint_t hv = *(const uint_t*)(hb + (size_t)sSrc[i] * 128 + c0);
            acc.x = fmaf(w, bf16lo(hv), acc.x);
            acc.y = fmaf(w, bf16hi(hv), acc.y);
        }
    }
#pragma unroll
    for (int off = 32; off > 0; off >>= 1) {
        ds.x += __shfl_xor(ds.x, off);
        ds.y += __shfl_xor(ds.y, off);
        ds.z += __shfl_xor(ds.z, off);
        ds.w += __shfl_xor(ds.w, off);
    }
    const float denom = hsel == 0 ? ds.x : hsel == 1 ? ds.y : hsel == 2 ? ds.z : ds.w;
    float o0 = acc.x / denom + bias[c0];
    float o1 = acc.y / denom + bias[c0 + 1];
    o0 = o0 > 0.f ? o0 : __expf(o0) - 1.f;   // ELU
    o1 = o1 > 0.f ? o1 : __expf(o1) - 1.f;
    const uint_t q0 = f2bf(o0), q1 = f2bf(o1);
    *(uint_t*)(x2b + (size_t)n * 128 + c0) = q0 | (q1 << 16);
}

// ---------------- GEMM2: h2[N,32](bf16) = x2b[N,128](bf16) @ W2, fused alpha2 ----------------
__global__ __launch_bounds__(256) void k_gemm2(const ushort_t* __restrict__ x2b,
                                               const float* __restrict__ W,
                                               const float* __restrict__ a_src,
                                               const float* __restrict__ a_dst,
                                               ushort_t* __restrict__ hb2,
                                               float* __restrict__ as_,
                                               float* __restrict__ ad_)
{
    __shared__ float sW[128 * 32];
    const int t = threadIdx.x;
    {
        const float4* W4 = (const float4*)W;
        float4* s4 = (float4*)sW;
#pragma unroll
        for (int i = 0; i < 4; ++i) s4[t + 256 * i] = W4[t + 256 * i];
    }
    __syncthreads();

    const int rr = t >> 5;
    const int c = t & 31;
    const int row = blockIdx.x * 8 + rr;
    const ushort_t* xp = x2b + (size_t)row * 128;

    float acc = 0.f;
    for (int k = 0; k < 128; k += 4) {
        const uint2 u = *(const uint2*)(xp + k);
        acc = fmaf(bf16lo(u.x), sW[(k + 0) * 32 + c], acc);
        acc = fmaf(bf16hi(u.x), sW[(k + 1) * 32 + c], acc);
        acc = fmaf(bf16lo(u.y), sW[(k + 2) * 32 + c], acc);
        acc = fmaf(bf16hi(u.y), sW[(k + 3) * 32 + c], acc);
    }

    hb2[(size_t)row * 32 + c] = f2bf(acc);
    float ps = acc * a_src[c], pd = acc * a_dst[c];
#pragma unroll
    for (int off = 16; off > 0; off >>= 1) {
        ps += __shfl_xor(ps, off);
        pd += __shfl_xor(pd, off);
    }
    if (c == 0) { as_[row] = ps; ad_[row] = pd; }
}

// ---------------- agg2: single-pass softmax + bias -> out[N,32] ----------------
__global__ __launch_bounds__(64) void k_agg2(const ushort_t* __restrict__ hb2,
                                             const float* __restrict__ as_,
                                             const float* __restrict__ ad_,
                                             const int* __restrict__ row_ptr,
                                             const int* __restrict__ col_src,
                                             const float* __restrict__ bias,
                                             float* __restrict__ out)
{
    __shared__ float sEx[64];
    __shared__ int sSrc[64];
    const int n = blockIdx.x;
    const int lane = threadIdx.x;
    const int start = row_ptr[n], end = row_ptr[n + 1];
    const float adn = ad_[n];

    const int c = lane & 31, half = lane >> 5;
    float acc = 0.f, dsum = 0.f;
    for (int base = start; base < end; base += 64) {
        const int e = base + lane;
        const int cnt = min(64, end - base);
        float ex = 0.f; int s = 0;
        if (e < end) {
            s = col_src[e];
            ex = __expf(lrelu(as_[s] + adn));
            dsum += ex;
        }
        __syncthreads();
        sEx[lane] = ex;
        sSrc[lane] = s;
        __syncthreads();
        for (int i = half; i < cnt; i += 2) {
            const ushort_t u = hb2[(size_t)sSrc[i] * 32 + c];
            acc = fmaf(sEx[i], __uint_as_float((uint_t)u << 16), acc);
        }
    }
#pragma unroll
    for (int off = 32; off > 0; off >>= 1) dsum += __shfl_xor(dsum, off);
    acc += __shfl_xor(acc, 32);
    if (half == 0) out[(size_t)n * 32 + c] = acc / dsum + bias[c];
}

extern "C" void kernel_launch(void* const* d_in, const int* in_sizes, int n_in,
                              void* d_out, int out_size, void* d_ws, size_t ws_size,
                              hipStream_t stream)
{
    const float* x      = (const float*)d_in[0];
    const int*   ei     = (const int*)d_in[1];
    const float* W1     = (const float*)d_in[2];
    const float* a_src1 = (const float*)d_in[3];
    const float* a_dst1 = (const float*)d_in[4];
    const float* b1     = (const float*)d_in[5];
    const float* W2     = (const float*)d_in[6];
    const float* a_src2 = (const float*)d_in[7];
    const float* a_dst2 = (const float*)d_in[8];
    const float* b2     = (const float*)d_in[9];
    float* out = (float*)d_out;

    char* p = (char*)d_ws;
    auto alloc = [&](size_t bytes) { char* q = p; p += (bytes + 255) & ~(size_t)255; return q; };
    ushort_t* h1b = (ushort_t*)alloc((size_t)N_NODES * 128 * 2);
    ushort_t* x2b = (ushort_t*)alloc((size_t)N_NODES * 128 * 2);
    ushort_t* h2b = (ushort_t*)alloc((size_t)N_NODES * 32 * 2);
    float* as1    = (float*)alloc((size_t)N_NODES * 4 * 4);
    float* ad1    = (float*)alloc((size_t)N_NODES * 4 * 4);
    float* as2    = (float*)alloc((size_t)N_NODES * 4);
    float* ad2    = (float*)alloc((size_t)N_NODES * 4);
    int* deg      = (int*)alloc((size_t)N_NODES * 4);
    int* row_ptr  = (int*)alloc((size_t)(N_NODES + 1) * 4);
    int* rank     = (int*)alloc((size_t)E_TOT * 4);
    int* bsum     = (int*)alloc(SCAN_NB * 4);
    int* col_src  = (int*)alloc((size_t)E_TOT * 4);

    (void)hipMemsetAsync(deg, 0, (size_t)N_NODES * 4, stream);

    k_gemm1_hist<<<G1_BLOCKS + HIST_BLOCKS, 256, 0, stream>>>(
        x, W1, a_src1, a_dst1, h1b, as1, ad1, ei, deg, rank);
    k_scan_a<<<SCAN_NB, 256, 0, stream>>>(deg, bsum);
    k_scan_c<<<SCAN_NB, 256, 0, stream>>>(deg, bsum, row_ptr);
    k_fill<<<(E_TOT + 255) / 256, 256, 0, stream>>>(ei, row_ptr, rank, col_src);
    k_agg1<<<N_NODES, 64, 0, stream>>>(h1b, as1, ad1, row_ptr, col_src, b1, x2b);
    k_gemm2<<<(N_NODES + 7) / 8, 256, 0, stream>>>(x2b, W2, a_src2, a_dst2, h2b, as2, ad2);
    k_agg2<<<N_NODES, 64, 0, stream>>>(h2b, as2, ad2, row_ptr, col_src, b2, out);
}